// Round 6
// baseline (337.860 us; speedup 1.0000x reference)
//
#include <hip/hip_runtime.h>
#include <math.h>

#define N_NODES 100000
#define N_EDGES 1600000
#define D_IN 128
#define HIDDEN 128
#define D_OUT 40
#define EPSN 1e-12f

// bucket = dst >> 8 (256 nodes per bucket)
#define NBUCK 391                            // ceil(100000/256)
#define EPB 4096                             // edges per bhist block
#define NPART ((N_EDGES + EPB - 1) / EPB)    // 391
#define PEPB 16384                           // edges per bpart block
#define PNPART ((N_EDGES + PEPB - 1) / PEPB) // 98

#define SWZ1_TOTAL (8 * 8 * 4 * 16 * 8)   // 32768
#define SWZ2_TOTAL (8 * 3 * 4 * 16 * 8)   // 12288
#define CASTB ((N_NODES * 16) / 256)      // 6250 blocks, 1 uint4 per thread
#define SWZB ((SWZ1_TOTAL + SWZ2_TOTAL + 255) / 256)  // 176

typedef __attribute__((ext_vector_type(8))) short short8;
typedef __attribute__((ext_vector_type(4))) float float4v;

static __device__ inline unsigned short f2bf(float f) {
    union { float f; unsigned u; } v; v.f = f;
    unsigned r = v.u + 0x7fffu + ((v.u >> 16) & 1u);
    return (unsigned short)(r >> 16);
}
// low bf16 of a packed u32 -> fp32 (shift); high bf16 -> fp32 (mask only)
static __device__ inline float bflo(unsigned u) {
    union { unsigned u; float f; } v; v.u = u << 16;
    return v.f;
}
static __device__ inline float bfhi(unsigned u) {
    union { unsigned u; float f; } v; v.u = u & 0xffff0000u;
    return v.f;
}

// ---------------- prep: bhist + cast + swz fused (blockIdx ranges) ----------------
__global__ void prep_kernel(const int* __restrict__ dst, int* __restrict__ bucketCount,
                            const float* __restrict__ x, unsigned* __restrict__ xb,
                            const float* __restrict__ Wl1, const float* __restrict__ Wr1,
                            const float* __restrict__ Wl2, const float* __restrict__ Wr2,
                            unsigned short* __restrict__ out1, unsigned short* __restrict__ out2) {
    __shared__ int h[NBUCK];
    int b = blockIdx.x, t = threadIdx.x;
    if (b < NPART) {
        // --- bucket histogram ---
        for (int i = t; i < NBUCK; i += 256) h[i] = 0;
        __syncthreads();
        int es = b * EPB;
        int ee = min(es + EPB, N_EDGES);
        for (int i = es + t; i < ee; i += 256) atomicAdd(&h[dst[i] >> 8], 1);
        __syncthreads();
        for (int i = t; i < NBUCK; i += 256)
            if (h[i]) atomicAdd(&bucketCount[i], h[i]);
        return;
    }
    b -= NPART;
    if (b < CASTB) {
        // --- fp32 -> packed bf16 cast, 1 uint4 (8 floats) per thread ---
        int g = b * 256 + t;
        const float4* x4 = (const float4*)x;
        float4 lo = x4[2 * g], hi = x4[2 * g + 1];
        uint4 o;
        o.x = (unsigned)f2bf(lo.x) | ((unsigned)f2bf(lo.y) << 16);
        o.y = (unsigned)f2bf(lo.z) | ((unsigned)f2bf(lo.w) << 16);
        o.z = (unsigned)f2bf(hi.x) | ((unsigned)f2bf(hi.y) << 16);
        o.w = (unsigned)f2bf(hi.z) | ((unsigned)f2bf(hi.w) << 16);
        ((uint4*)xb)[g] = o;
        return;
    }
    b -= CASTB;
    {
        // --- weight swizzle into MFMA B-fragment order ---
        int idx = b * 256 + t;
        const float* Wl; const float* Wr; unsigned short* out; int NC, NOUT;
        if (idx < SWZ1_TOTAL) {
            Wl = Wl1; Wr = Wr1; out = out1; NC = 8; NOUT = HIDDEN;
        } else if (idx < SWZ1_TOTAL + SWZ2_TOTAL) {
            idx -= SWZ1_TOTAL;
            Wl = Wl2; Wr = Wr2; out = out2; NC = 3; NOUT = D_OUT;
        } else return;
        int j = idx & 7, l15 = (idx >> 3) & 15, quad = (idx >> 7) & 3;
        int rem = idx >> 9;
        int c = rem % NC, kt = rem / NC;
        int k = kt * 32 + quad * 8 + j;
        int n = c * 16 + l15;
        float val = 0.0f;
        if (n < NOUT) val = (k < 128) ? Wl[k * NOUT + n] : Wr[(k - 128) * NOUT + n];
        out[idx] = f2bf(val);
    }
}

// ---------------- scan 391 bucket counts (one block) ----------------
__global__ void bscan_kernel(const int* __restrict__ bc, int* __restrict__ bstart,
                             int* __restrict__ cursor) {
    __shared__ int s[256];
    int t = threadIdx.x;
    int a = (2 * t < NBUCK) ? bc[2 * t] : 0;
    int b = (2 * t + 1 < NBUCK) ? bc[2 * t + 1] : 0;
    int tp = a + b;
    s[t] = tp;
    __syncthreads();
    for (int off = 1; off < 256; off <<= 1) {
        int tmp = (t >= off) ? s[t - off] : 0;
        __syncthreads();
        s[t] += tmp;
        __syncthreads();
    }
    int texcl = s[t] - tp;
    if (2 * t < NBUCK) { bstart[2 * t] = texcl; cursor[2 * t] = texcl; }
    if (2 * t + 1 < NBUCK) { bstart[2 * t + 1] = texcl + a; cursor[2 * t + 1] = texcl + a; }
    if (t == 255) bstart[NBUCK] = s[255];
}

// ---------------- partition edges into buckets (packed u32), long runs ----------------
__global__ __launch_bounds__(512) void bpart_kernel(
    const int* __restrict__ src, const int* __restrict__ dst,
    int* __restrict__ cursor, unsigned* __restrict__ pairs) {
    __shared__ int h[NBUCK];
    __shared__ int base[NBUCK];
    int t = threadIdx.x;
    for (int i = t; i < NBUCK; i += 512) h[i] = 0;
    __syncthreads();
    int es = blockIdx.x * PEPB;
    int ee = min(es + PEPB, N_EDGES);
    for (int i = es + t; i < ee; i += 512) atomicAdd(&h[dst[i] >> 8], 1);
    __syncthreads();
    for (int i = t; i < NBUCK; i += 512) {
        int c = h[i];
        base[i] = c ? atomicAdd(&cursor[i], c) : 0;
    }
    __syncthreads();
    for (int i = t; i < NBUCK; i += 512) h[i] = 0;
    __syncthreads();
    for (int i = es + t; i < ee; i += 512) {
        int d = dst[i];
        int bk = d >> 8;
        int r = atomicAdd(&h[bk], 1);
        pairs[base[bk] + r] = ((unsigned)src[i] << 8) | (unsigned)(d & 255);
    }
}

// ---------------- per-bucket CSR finalize: count+scan+fill all in LDS ----------------
__global__ void csr_kernel(const unsigned* __restrict__ pairs, const int* __restrict__ bstart,
                           int* __restrict__ hist, int* __restrict__ rowStart,
                           int* __restrict__ sortedSrc) {
    __shared__ int cnt[256];
    __shared__ int sc[256];
    __shared__ int cur[256];
    int b = blockIdx.x, t = threadIdx.x;
    int es = bstart[b], ee = bstart[b + 1];
    cnt[t] = 0;
    __syncthreads();
    for (int i = es + t; i < ee; i += 256) atomicAdd(&cnt[pairs[i] & 255], 1);
    __syncthreads();
    int v = cnt[t];
    sc[t] = v;
    __syncthreads();
    for (int off = 1; off < 256; off <<= 1) {
        int tmp = (t >= off) ? sc[t - off] : 0;
        __syncthreads();
        sc[t] += tmp;
        __syncthreads();
    }
    int excl = sc[t] - v;
    int node = (b << 8) + t;
    if (node < N_NODES) {
        hist[node] = v;
        rowStart[node] = es + excl;
    }
    cur[t] = excl;
    __syncthreads();
    for (int i = es + t; i < ee; i += 256) {
        unsigned p = pairs[i];
        int r = atomicAdd(&cur[p & 255], 1);
        sortedSrc[es + r] = (int)(p >> 8);
    }
}

// ===== shared gather routine: wave computes node's mean row into a0..a7 =====
// 16 lanes (sl) x 16B cover the 256B row; quarters q=0..3 handle parallel edges.
#define GATHER_BODY(feat4)                                                        \
    float a0 = 0.f, a1 = 0.f, a2 = 0.f, a3 = 0.f,                                 \
          a4 = 0.f, a5 = 0.f, a6 = 0.f, a7 = 0.f;                                 \
    int i = 0;                                                                    \
    for (; i + 8 <= cnt; i += 8) {                                                \
        int sA = sortedSrc[s0 + i + q];                                           \
        int sB = sortedSrc[s0 + i + 4 + q];                                       \
        uint4 vA = feat4[(size_t)sA * 16 + sl];                                   \
        uint4 vB = feat4[(size_t)sB * 16 + sl];                                   \
        a0 += bflo(vA.x) + bflo(vB.x); a1 += bfhi(vA.x) + bfhi(vB.x);             \
        a2 += bflo(vA.y) + bflo(vB.y); a3 += bfhi(vA.y) + bfhi(vB.y);             \
        a4 += bflo(vA.z) + bflo(vB.z); a5 += bfhi(vA.z) + bfhi(vB.z);             \
        a6 += bflo(vA.w) + bflo(vB.w); a7 += bfhi(vA.w) + bfhi(vB.w);             \
    }                                                                             \
    for (; i + 4 <= cnt; i += 4) {                                                \
        int s = sortedSrc[s0 + i + q];                                            \
        uint4 v = feat4[(size_t)s * 16 + sl];                                     \
        a0 += bflo(v.x); a1 += bfhi(v.x); a2 += bflo(v.y); a3 += bfhi(v.y);       \
        a4 += bflo(v.z); a5 += bfhi(v.z); a6 += bflo(v.w); a7 += bfhi(v.w);       \
    }                                                                             \
    if (q < cnt - i) {                                                            \
        int s = sortedSrc[s0 + i + q];                                            \
        uint4 v = feat4[(size_t)s * 16 + sl];                                     \
        a0 += bflo(v.x); a1 += bfhi(v.x); a2 += bflo(v.y); a3 += bfhi(v.y);       \
        a4 += bflo(v.z); a5 += bfhi(v.z); a6 += bflo(v.w); a7 += bfhi(v.w);       \
    }                                                                             \
    a0 += __shfl_xor(a0, 16, 64); a0 += __shfl_xor(a0, 32, 64);                   \
    a1 += __shfl_xor(a1, 16, 64); a1 += __shfl_xor(a1, 32, 64);                   \
    a2 += __shfl_xor(a2, 16, 64); a2 += __shfl_xor(a2, 32, 64);                   \
    a3 += __shfl_xor(a3, 16, 64); a3 += __shfl_xor(a3, 32, 64);                   \
    a4 += __shfl_xor(a4, 16, 64); a4 += __shfl_xor(a4, 32, 64);                   \
    a5 += __shfl_xor(a5, 16, 64); a5 += __shfl_xor(a5, 32, 64);                   \
    a6 += __shfl_xor(a6, 16, 64); a6 += __shfl_xor(a6, 32, 64);                   \
    a7 += __shfl_xor(a7, 16, 64); a7 += __shfl_xor(a7, 32, 64);

// ---------------- layer 1 fused: gather-mean (LDS) + MFMA GEMM + L2norm + relu ----------------
// Block = 64 nodes, 4 waves; wave w owns nodes [w*16, w*16+16) — LDS rows are
// wave-private so no __syncthreads is needed between gather and GEMM.
__global__ __launch_bounds__(256) void fused1_kernel(
    const unsigned short* __restrict__ xb, const int* __restrict__ sortedSrc,
    const int* __restrict__ rowStart, const int* __restrict__ hist,
    const short* __restrict__ bswz, const float* __restrict__ bias,
    unsigned short* __restrict__ hb) {
    __shared__ unsigned short smean[4][16][136];  // stride 136 elems = 272 B (16B-aligned)
    int tid = threadIdx.x;
    int w = __builtin_amdgcn_readfirstlane(tid >> 6);
    int lane = tid & 63;
    int q = lane >> 4, sl = lane & 15;
    int n0 = blockIdx.x * 64;
    const uint4* feat4 = (const uint4*)xb;

    // ---- gather phase: 16 nodes per wave ----
    for (int nn = 0; nn < 16; nn++) {
        int node = n0 + w * 16 + nn;
        int s0 = 0, cnt = 0;
        if (node < N_NODES) { s0 = rowStart[node]; cnt = hist[node]; }
        GATHER_BODY(feat4)
        if (q == 0) {
            float dinv = 1.0f / fmaxf((float)cnt, 1.0f);
            uint4 o;
            o.x = (unsigned)f2bf(a0 * dinv) | ((unsigned)f2bf(a1 * dinv) << 16);
            o.y = (unsigned)f2bf(a2 * dinv) | ((unsigned)f2bf(a3 * dinv) << 16);
            o.z = (unsigned)f2bf(a4 * dinv) | ((unsigned)f2bf(a5 * dinv) << 16);
            o.w = (unsigned)f2bf(a6 * dinv) | ((unsigned)f2bf(a7 * dinv) << 16);
            *(uint4*)&smean[w][nn][sl * 8] = o;
        }
    }

    // ---- GEMM phase ----
    int l15 = sl, quad = q;
    int nodeA = n0 + w * 16 + l15;
    int nodeAc = (nodeA < N_NODES) ? nodeA : (N_NODES - 1);

    float4v acc[8];
#pragma unroll
    for (int c = 0; c < 8; c++) acc[c] = (float4v){0.f, 0.f, 0.f, 0.f};

#pragma unroll
    for (int kt = 0; kt < 8; kt++) {
        short8 a;
        if (kt < 4)
            a = *(const short8*)&smean[w][l15][kt * 32 + quad * 8];
        else
            a = *(const short8*)(xb + (size_t)nodeAc * 128 + (kt & 3) * 32 + quad * 8);
#pragma unroll
        for (int c = 0; c < 8; c++) {
            short8 b = *(const short8*)(bswz + (((kt * 8 + c) * 4 + quad) * 16 + l15) * 8);
            acc[c] = __builtin_amdgcn_mfma_f32_16x16x32_bf16(a, b, acc[c], 0, 0, 0);
        }
    }

    float v[8][4];
    float ss[4] = {0.f, 0.f, 0.f, 0.f};
#pragma unroll
    for (int c = 0; c < 8; c++) {
        float bi = bias[c * 16 + l15];
#pragma unroll
        for (int r = 0; r < 4; r++) {
            float t = acc[c][r] + bi;
            v[c][r] = t;
            ss[r] += t * t;
        }
    }
#pragma unroll
    for (int r = 0; r < 4; r++)
        for (int off = 1; off < 16; off <<= 1) ss[r] += __shfl_xor(ss[r], off, 64);
#pragma unroll
    for (int r = 0; r < 4; r++) {
        int node = n0 + w * 16 + quad * 4 + r;
        if (node < N_NODES) {
            float inv = 1.0f / fmaxf(sqrtf(ss[r]), EPSN);
#pragma unroll
            for (int c = 0; c < 8; c++) {
                hb[(size_t)node * 128 + c * 16 + l15] = f2bf(fmaxf(v[c][r] * inv, 0.0f));
            }
        }
    }
}

// ---------------- layer 2 fused: gather-mean (LDS) + MFMA GEMM + L2norm + log_softmax ----------------
__global__ __launch_bounds__(256) void fused2_kernel(
    const unsigned short* __restrict__ hb, const int* __restrict__ sortedSrc,
    const int* __restrict__ rowStart, const int* __restrict__ hist,
    const short* __restrict__ bswz, const float* __restrict__ bias,
    float* __restrict__ out) {
    __shared__ unsigned short smean[4][16][136];
    int tid = threadIdx.x;
    int w = __builtin_amdgcn_readfirstlane(tid >> 6);
    int lane = tid & 63;
    int q = lane >> 4, sl = lane & 15;
    int n0 = blockIdx.x * 64;
    const uint4* feat4 = (const uint4*)hb;

    for (int nn = 0; nn < 16; nn++) {
        int node = n0 + w * 16 + nn;
        int s0 = 0, cnt = 0;
        if (node < N_NODES) { s0 = rowStart[node]; cnt = hist[node]; }
        GATHER_BODY(feat4)
        if (q == 0) {
            float dinv = 1.0f / fmaxf((float)cnt, 1.0f);
            uint4 o;
            o.x = (unsigned)f2bf(a0 * dinv) | ((unsigned)f2bf(a1 * dinv) << 16);
            o.y = (unsigned)f2bf(a2 * dinv) | ((unsigned)f2bf(a3 * dinv) << 16);
            o.z = (unsigned)f2bf(a4 * dinv) | ((unsigned)f2bf(a5 * dinv) << 16);
            o.w = (unsigned)f2bf(a6 * dinv) | ((unsigned)f2bf(a7 * dinv) << 16);
            *(uint4*)&smean[w][nn][sl * 8] = o;
        }
    }

    int l15 = sl, quad = q;
    int nodeA = n0 + w * 16 + l15;
    int nodeAc = (nodeA < N_NODES) ? nodeA : (N_NODES - 1);

    float4v acc[3];
#pragma unroll
    for (int c = 0; c < 3; c++) acc[c] = (float4v){0.f, 0.f, 0.f, 0.f};

#pragma unroll
    for (int kt = 0; kt < 8; kt++) {
        short8 a;
        if (kt < 4)
            a = *(const short8*)&smean[w][l15][kt * 32 + quad * 8];
        else
            a = *(const short8*)(hb + (size_t)nodeAc * 128 + (kt & 3) * 32 + quad * 8);
#pragma unroll
        for (int c = 0; c < 3; c++) {
            short8 b = *(const short8*)(bswz + (((kt * 3 + c) * 4 + quad) * 16 + l15) * 8);
            acc[c] = __builtin_amdgcn_mfma_f32_16x16x32_bf16(a, b, acc[c], 0, 0, 0);
        }
    }

    float v[3][4];
    float ss[4] = {0.f, 0.f, 0.f, 0.f};
#pragma unroll
    for (int c = 0; c < 3; c++) {
        int col = c * 16 + l15;
        float bi = (col < D_OUT) ? bias[col] : 0.0f;
#pragma unroll
        for (int r = 0; r < 4; r++) {
            float t = acc[c][r] + bi;
            v[c][r] = t;
            ss[r] += t * t;
        }
    }
#pragma unroll
    for (int r = 0; r < 4; r++)
        for (int off = 1; off < 16; off <<= 1) ss[r] += __shfl_xor(ss[r], off, 64);

#pragma unroll
    for (int r = 0; r < 4; r++) {
        int node = n0 + w * 16 + quad * 4 + r;
        float inv = 1.0f / fmaxf(sqrtf(ss[r]), EPSN);
        float vn[3];
        float m = -INFINITY;
#pragma unroll
        for (int c = 0; c < 3; c++) {
            int col = c * 16 + l15;
            vn[c] = v[c][r] * inv;
            if (col < D_OUT) m = fmaxf(m, vn[c]);
        }
        for (int off = 1; off < 16; off <<= 1) m = fmaxf(m, __shfl_xor(m, off, 64));
        float se = 0.0f;
#pragma unroll
        for (int c = 0; c < 3; c++) {
            int col = c * 16 + l15;
            if (col < D_OUT) se += expf(vn[c] - m);
        }
        for (int off = 1; off < 16; off <<= 1) se += __shfl_xor(se, off, 64);
        float ls = logf(se);
        if (node < N_NODES) {
#pragma unroll
            for (int c = 0; c < 3; c++) {
                int col = c * 16 + l15;
                if (col < D_OUT) out[(size_t)node * D_OUT + col] = vn[c] - m - ls;
            }
        }
    }
}

static inline size_t align256(size_t x) { return (x + 255) & ~(size_t)255; }

extern "C" void kernel_launch(void* const* d_in, const int* in_sizes, int n_in,
                              void* d_out, int out_size, void* d_ws, size_t ws_size,
                              hipStream_t stream) {
    const float* x   = (const float*)d_in[0];
    const int*   ei  = (const int*)d_in[1];
    const float* Wl1 = (const float*)d_in[2];
    const float* bl1 = (const float*)d_in[3];
    const float* Wr1 = (const float*)d_in[4];
    const float* Wl2 = (const float*)d_in[5];
    const float* bl2 = (const float*)d_in[6];
    const float* Wr2 = (const float*)d_in[7];
    float* out = (float*)d_out;

    const int* src = ei;
    const int* dst = ei + N_EDGES;

    char* ws = (char*)d_ws;
    size_t off = 0;
    int* bucketCount = (int*)(ws + off); off += align256((size_t)NBUCK * 4);
    int* bucketStart = (int*)(ws + off); off += align256((size_t)(NBUCK + 1) * 4);
    int* cursor      = (int*)(ws + off); off += align256((size_t)NBUCK * 4);
    int* hist        = (int*)(ws + off); off += align256((size_t)N_NODES * 4);
    int* rowStart    = (int*)(ws + off); off += align256((size_t)N_NODES * 4);
    unsigned* pairs  = (unsigned*)(ws + off); off += align256((size_t)N_EDGES * 4);
    int* sortedSrc   = (int*)(ws + off); off += align256((size_t)N_EDGES * 4);
    unsigned* xb     = (unsigned*)(ws + off); off += align256((size_t)N_NODES * 128 * 2);
    unsigned* hb     = (unsigned*)(ws + off); off += align256((size_t)N_NODES * 128 * 2);
    unsigned short* bswz1 = (unsigned short*)(ws + off); off += align256((size_t)SWZ1_TOTAL * 2);
    unsigned short* bswz2 = (unsigned short*)(ws + off); off += align256((size_t)SWZ2_TOTAL * 2);

    hipMemsetAsync(bucketCount, 0, (size_t)NBUCK * 4, stream);

    prep_kernel<<<NPART + CASTB + SWZB, 256, 0, stream>>>(
        dst, bucketCount, x, xb, Wl1, Wr1, Wl2, Wr2, bswz1, bswz2);
    bscan_kernel<<<1, 256, 0, stream>>>(bucketCount, bucketStart, cursor);
    bpart_kernel<<<PNPART, 512, 0, stream>>>(src, dst, cursor, pairs);
    csr_kernel<<<NBUCK, 256, 0, stream>>>(pairs, bucketStart, hist, rowStart, sortedSrc);

    fused1_kernel<<<(N_NODES + 63) / 64, 256, 0, stream>>>(
        (const unsigned short*)xb, sortedSrc, rowStart, hist,
        (const short*)bswz1, bl1, (unsigned short*)hb);
    fused2_kernel<<<(N_NODES + 63) / 64, 256, 0, stream>>>(
        (const unsigned short*)hb, sortedSrc, rowStart, hist,
        (const short*)bswz2, bl2, out);
}

// Round 7
// 316.606 us; speedup vs baseline: 1.0671x; 1.0671x over previous
//
#include <hip/hip_runtime.h>
#include <math.h>

#define N_NODES 100000
#define N_EDGES 1600000
#define D_IN 128
#define HIDDEN 128
#define D_OUT 40
#define EPSN 1e-12f

// bucket = dst >> 8 (256 nodes per bucket)
#define NBUCK 391                            // ceil(100000/256)
#define EPB 4096                             // edges per bhist block
#define NPART ((N_EDGES + EPB - 1) / EPB)    // 391
#define PEPB 16384                           // edges per bpart block
#define PNPART ((N_EDGES + PEPB - 1) / PEPB) // 98

#define SWZ1_TOTAL (8 * 8 * 4 * 16 * 8)   // 32768  (K=256, N=128)
#define SWZ2_TOTAL (4 * 8 * 4 * 16 * 8)   // 16384  (K=128, N=128: [g_l64|g_r64])
#define CASTB ((N_NODES * 16) / 256)      // 6250 blocks, 1 uint4 per thread
#define SWZB ((SWZ1_TOTAL + SWZ2_TOTAL + 255) / 256)  // 192

typedef __attribute__((ext_vector_type(8))) short short8;
typedef __attribute__((ext_vector_type(4))) float float4v;

static __device__ inline unsigned short f2bf(float f) {
    union { float f; unsigned u; } v; v.f = f;
    unsigned r = v.u + 0x7fffu + ((v.u >> 16) & 1u);
    return (unsigned short)(r >> 16);
}
static __device__ inline float bflo(unsigned u) {
    union { unsigned u; float f; } v; v.u = u << 16;
    return v.f;
}
static __device__ inline float bfhi(unsigned u) {
    union { unsigned u; float f; } v; v.u = u & 0xffff0000u;
    return v.f;
}

// ---------------- prep: bhist + cast + both weight swizzles, fused ----------------
__global__ void prep_kernel(const int* __restrict__ dst, int* __restrict__ bucketCount,
                            const float* __restrict__ x, unsigned* __restrict__ xb,
                            const float* __restrict__ Wl1, const float* __restrict__ Wr1,
                            const float* __restrict__ Wl2, const float* __restrict__ Wr2,
                            unsigned short* __restrict__ out1, unsigned short* __restrict__ out2) {
    __shared__ int h[NBUCK];
    int b = blockIdx.x, t = threadIdx.x;
    if (b < NPART) {
        for (int i = t; i < NBUCK; i += 256) h[i] = 0;
        __syncthreads();
        int es = b * EPB;
        int ee = min(es + EPB, N_EDGES);
        for (int i = es + t; i < ee; i += 256) atomicAdd(&h[dst[i] >> 8], 1);
        __syncthreads();
        for (int i = t; i < NBUCK; i += 256)
            if (h[i]) atomicAdd(&bucketCount[i], h[i]);
        return;
    }
    b -= NPART;
    if (b < CASTB) {
        int g = b * 256 + t;
        const float4* x4 = (const float4*)x;
        float4 lo = x4[2 * g], hi = x4[2 * g + 1];
        uint4 o;
        o.x = (unsigned)f2bf(lo.x) | ((unsigned)f2bf(lo.y) << 16);
        o.y = (unsigned)f2bf(lo.z) | ((unsigned)f2bf(lo.w) << 16);
        o.z = (unsigned)f2bf(hi.x) | ((unsigned)f2bf(hi.y) << 16);
        o.w = (unsigned)f2bf(hi.z) | ((unsigned)f2bf(hi.w) << 16);
        ((uint4*)xb)[g] = o;
        return;
    }
    b -= CASTB;
    {
        int idx = b * 256 + t;
        if (idx < SWZ1_TOTAL) {
            // layer-1 weights: W_cat=[Wl1;Wr1], K=256, N=128
            int j = idx & 7, l15 = (idx >> 3) & 15, quad = (idx >> 7) & 3;
            int rem = idx >> 9;
            int c = rem & 7, kt = rem >> 3;           // c:0..7, kt:0..7
            int k = kt * 32 + quad * 8 + j;
            int n = c * 16 + l15;
            float val = (k < 128) ? Wl1[k * HIDDEN + n] : Wr1[(k - 128) * HIDDEN + n];
            out1[idx] = f2bf(val);
        } else if (idx < SWZ1_TOTAL + SWZ2_TOTAL) {
            // layer-2 combined: K=128, N=128 cols: [0..39]=Wl2, [64..103]=Wr2, rest 0
            idx -= SWZ1_TOTAL;
            int j = idx & 7, l15 = (idx >> 3) & 15, quad = (idx >> 7) & 3;
            int rem = idx >> 9;
            int c = rem & 7, kt = rem >> 3;           // c:0..7, kt:0..3
            int k = kt * 32 + quad * 8 + j;
            int n = c * 16 + l15;
            float val = 0.0f;
            if (n < D_OUT) val = Wl2[k * D_OUT + n];
            else if (n >= 64 && n < 64 + D_OUT) val = Wr2[k * D_OUT + (n - 64)];
            out2[idx] = f2bf(val);
        }
    }
}

// ---------------- scan 391 bucket counts (one block) ----------------
__global__ void bscan_kernel(const int* __restrict__ bc, int* __restrict__ bstart,
                             int* __restrict__ cursor) {
    __shared__ int s[256];
    int t = threadIdx.x;
    int a = (2 * t < NBUCK) ? bc[2 * t] : 0;
    int b = (2 * t + 1 < NBUCK) ? bc[2 * t + 1] : 0;
    int tp = a + b;
    s[t] = tp;
    __syncthreads();
    for (int off = 1; off < 256; off <<= 1) {
        int tmp = (t >= off) ? s[t - off] : 0;
        __syncthreads();
        s[t] += tmp;
        __syncthreads();
    }
    int texcl = s[t] - tp;
    if (2 * t < NBUCK) { bstart[2 * t] = texcl; cursor[2 * t] = texcl; }
    if (2 * t + 1 < NBUCK) { bstart[2 * t + 1] = texcl + a; cursor[2 * t + 1] = texcl + a; }
    if (t == 255) bstart[NBUCK] = s[255];
}

// ---------------- partition edges into buckets (packed u32), long runs ----------------
__global__ __launch_bounds__(512) void bpart_kernel(
    const int* __restrict__ src, const int* __restrict__ dst,
    int* __restrict__ cursor, unsigned* __restrict__ pairs) {
    __shared__ int h[NBUCK];
    __shared__ int base[NBUCK];
    int t = threadIdx.x;
    for (int i = t; i < NBUCK; i += 512) h[i] = 0;
    __syncthreads();
    int es = blockIdx.x * PEPB;
    int ee = min(es + PEPB, N_EDGES);
    for (int i = es + t; i < ee; i += 512) atomicAdd(&h[dst[i] >> 8], 1);
    __syncthreads();
    for (int i = t; i < NBUCK; i += 512) {
        int c = h[i];
        base[i] = c ? atomicAdd(&cursor[i], c) : 0;
    }
    __syncthreads();
    for (int i = t; i < NBUCK; i += 512) h[i] = 0;
    __syncthreads();
    for (int i = es + t; i < ee; i += 512) {
        int d = dst[i];
        int bk = d >> 8;
        int r = atomicAdd(&h[bk], 1);
        pairs[base[bk] + r] = ((unsigned)src[i] << 8) | (unsigned)(d & 255);
    }
}

// ---------------- per-bucket CSR finalize: count+scan+fill all in LDS ----------------
__global__ void csr_kernel(const unsigned* __restrict__ pairs, const int* __restrict__ bstart,
                           int* __restrict__ hist, int* __restrict__ rowStart,
                           int* __restrict__ sortedSrc) {
    __shared__ int cnt[256];
    __shared__ int sc[256];
    __shared__ int cur[256];
    int b = blockIdx.x, t = threadIdx.x;
    int es = bstart[b], ee = bstart[b + 1];
    cnt[t] = 0;
    __syncthreads();
    for (int i = es + t; i < ee; i += 256) atomicAdd(&cnt[pairs[i] & 255], 1);
    __syncthreads();
    int v = cnt[t];
    sc[t] = v;
    __syncthreads();
    for (int off = 1; off < 256; off <<= 1) {
        int tmp = (t >= off) ? sc[t - off] : 0;
        __syncthreads();
        sc[t] += tmp;
        __syncthreads();
    }
    int excl = sc[t] - v;
    int node = (b << 8) + t;
    if (node < N_NODES) {
        hist[node] = v;
        rowStart[node] = es + excl;
    }
    cur[t] = excl;
    __syncthreads();
    for (int i = es + t; i < ee; i += 256) {
        unsigned p = pairs[i];
        int r = atomicAdd(&cur[p & 255], 1);
        sortedSrc[es + r] = (int)(p >> 8);
    }
}

// ---------------- layer-1 gather-mean: one wave per node, dwordx4, 8 edges/iter ----------------
__global__ void agg_kernel(const uint4* __restrict__ feat,  // [N][16] uint4 (256B rows)
                           const int* __restrict__ sortedSrc,
                           const int* __restrict__ rowStart, const int* __restrict__ hist,
                           uint4* __restrict__ meanb) {
    int w = __builtin_amdgcn_readfirstlane((int)(threadIdx.x >> 6));
    int node = blockIdx.x * 4 + w;
    int lane = threadIdx.x & 63;
    int q = lane >> 4, sl = lane & 15;
    int s0 = __builtin_amdgcn_readfirstlane(rowStart[node]);
    int cnt = __builtin_amdgcn_readfirstlane(hist[node]);
    float a0 = 0.f, a1 = 0.f, a2 = 0.f, a3 = 0.f, a4 = 0.f, a5 = 0.f, a6 = 0.f, a7 = 0.f;
    int i = 0;
    for (; i + 8 <= cnt; i += 8) {
        int sA = sortedSrc[s0 + i + q];
        int sB = sortedSrc[s0 + i + 4 + q];
        uint4 vA = feat[(size_t)sA * 16 + sl];
        uint4 vB = feat[(size_t)sB * 16 + sl];
        a0 += bflo(vA.x) + bflo(vB.x); a1 += bfhi(vA.x) + bfhi(vB.x);
        a2 += bflo(vA.y) + bflo(vB.y); a3 += bfhi(vA.y) + bfhi(vB.y);
        a4 += bflo(vA.z) + bflo(vB.z); a5 += bfhi(vA.z) + bfhi(vB.z);
        a6 += bflo(vA.w) + bflo(vB.w); a7 += bfhi(vA.w) + bfhi(vB.w);
    }
    for (; i + 4 <= cnt; i += 4) {
        int s = sortedSrc[s0 + i + q];
        uint4 v = feat[(size_t)s * 16 + sl];
        a0 += bflo(v.x); a1 += bfhi(v.x); a2 += bflo(v.y); a3 += bfhi(v.y);
        a4 += bflo(v.z); a5 += bfhi(v.z); a6 += bflo(v.w); a7 += bfhi(v.w);
    }
    if (q < cnt - i) {
        int s = sortedSrc[s0 + i + q];
        uint4 v = feat[(size_t)s * 16 + sl];
        a0 += bflo(v.x); a1 += bfhi(v.x); a2 += bflo(v.y); a3 += bfhi(v.y);
        a4 += bflo(v.z); a5 += bfhi(v.z); a6 += bflo(v.w); a7 += bfhi(v.w);
    }
    a0 += __shfl_xor(a0, 16, 64); a0 += __shfl_xor(a0, 32, 64);
    a1 += __shfl_xor(a1, 16, 64); a1 += __shfl_xor(a1, 32, 64);
    a2 += __shfl_xor(a2, 16, 64); a2 += __shfl_xor(a2, 32, 64);
    a3 += __shfl_xor(a3, 16, 64); a3 += __shfl_xor(a3, 32, 64);
    a4 += __shfl_xor(a4, 16, 64); a4 += __shfl_xor(a4, 32, 64);
    a5 += __shfl_xor(a5, 16, 64); a5 += __shfl_xor(a5, 32, 64);
    a6 += __shfl_xor(a6, 16, 64); a6 += __shfl_xor(a6, 32, 64);
    a7 += __shfl_xor(a7, 16, 64); a7 += __shfl_xor(a7, 32, 64);
    if (q == 0) {
        float dinv = 1.0f / fmaxf((float)cnt, 1.0f);
        uint4 o;
        o.x = (unsigned)f2bf(a0 * dinv) | ((unsigned)f2bf(a1 * dinv) << 16);
        o.y = (unsigned)f2bf(a2 * dinv) | ((unsigned)f2bf(a3 * dinv) << 16);
        o.z = (unsigned)f2bf(a4 * dinv) | ((unsigned)f2bf(a5 * dinv) << 16);
        o.w = (unsigned)f2bf(a6 * dinv) | ((unsigned)f2bf(a7 * dinv) << 16);
        meanb[(size_t)node * 16 + sl] = o;
    }
}

// ---------------- layer-1 GEMM + norm + relu + layer-2 projection (2 MFMA passes) ----------------
// GEMM1: [64 nodes x 128] = [mean|x] (K=256) @ W1cat; epilogue -> h (bf16, LDS)
// GEMM2: g = h (K=128) @ W2cat; cols 0..39 -> g_l, 64..103 -> g_r (both padded to 64)
__global__ __launch_bounds__(256) void gemm1g_kernel(
    const unsigned short* __restrict__ meanb, const unsigned short* __restrict__ xb,
    const short* __restrict__ bswz1, const float* __restrict__ bias1,
    const short* __restrict__ bswz2,
    unsigned short* __restrict__ g_l, unsigned short* __restrict__ g_r) {
    __shared__ unsigned short hT[4][16][140];  // stride 140 elem: conflict-free frag reads
    int tid = threadIdx.x;
    int w = __builtin_amdgcn_readfirstlane(tid >> 6);
    int lane = tid & 63;
    int l15 = lane & 15, quad = lane >> 4;
    int n0 = blockIdx.x * 64;
    int nodeA = n0 + w * 16 + l15;
    if (nodeA >= N_NODES) nodeA = N_NODES - 1;

    float4v acc[8];
#pragma unroll
    for (int c = 0; c < 8; c++) acc[c] = (float4v){0.f, 0.f, 0.f, 0.f};
#pragma unroll
    for (int kt = 0; kt < 8; kt++) {
        const unsigned short* ab = (kt < 4) ? meanb : xb;
        short8 a = *(const short8*)(ab + (size_t)nodeA * 128 + (kt & 3) * 32 + quad * 8);
#pragma unroll
        for (int c = 0; c < 8; c++) {
            short8 b = *(const short8*)(bswz1 + (((kt * 8 + c) * 4 + quad) * 16 + l15) * 8);
            acc[c] = __builtin_amdgcn_mfma_f32_16x16x32_bf16(a, b, acc[c], 0, 0, 0);
        }
    }

    // epilogue 1: bias, L2-norm, relu -> bf16 h tile in LDS (wave-private rows)
    float v[8][4];
    float ss[4] = {0.f, 0.f, 0.f, 0.f};
#pragma unroll
    for (int c = 0; c < 8; c++) {
        float bi = bias1[c * 16 + l15];
#pragma unroll
        for (int r = 0; r < 4; r++) {
            float t = acc[c][r] + bi;
            v[c][r] = t;
            ss[r] += t * t;
        }
    }
#pragma unroll
    for (int r = 0; r < 4; r++)
        for (int off = 1; off < 16; off <<= 1) ss[r] += __shfl_xor(ss[r], off, 64);
#pragma unroll
    for (int r = 0; r < 4; r++) {
        float inv = 1.0f / fmaxf(sqrtf(ss[r]), EPSN);
#pragma unroll
        for (int c = 0; c < 8; c++) {
            hT[w][quad * 4 + r][c * 16 + l15] = f2bf(fmaxf(v[c][r] * inv, 0.0f));
        }
    }
    // same-wave LDS RAW: compiler inserts lgkmcnt wait; no __syncthreads needed.

    // GEMM2: K=128 from LDS h
    float4v acc2[8];
#pragma unroll
    for (int c = 0; c < 8; c++) acc2[c] = (float4v){0.f, 0.f, 0.f, 0.f};
#pragma unroll
    for (int kt = 0; kt < 4; kt++) {
        short8 a = *(const short8*)&hT[w][l15][kt * 32 + quad * 8];
#pragma unroll
        for (int c = 0; c < 8; c++) {
            short8 b = *(const short8*)(bswz2 + (((kt * 8 + c) * 4 + quad) * 16 + l15) * 8);
            acc2[c] = __builtin_amdgcn_mfma_f32_16x16x32_bf16(a, b, acc2[c], 0, 0, 0);
        }
    }
#pragma unroll
    for (int r = 0; r < 4; r++) {
        int node = n0 + w * 16 + quad * 4 + r;
        if (node < N_NODES) {
#pragma unroll
            for (int c = 0; c < 4; c++)
                g_l[(size_t)node * 64 + c * 16 + l15] = f2bf(acc2[c][r]);
#pragma unroll
            for (int c = 4; c < 8; c++)
                g_r[(size_t)node * 64 + (c - 4) * 16 + l15] = f2bf(acc2[c][r]);
        }
    }
}

// ---------------- layer 2 final: gather-mean of g_l + g_r + bias + norm + log_softmax ----------------
// Wave per node; 8 lanes (sl) x uint4 cover the 128B g_l row; 8 edge-groups (q).
__global__ void fused2g_kernel(const uint4* __restrict__ g_l4, const uint4* __restrict__ g_r4,
                               const int* __restrict__ sortedSrc,
                               const int* __restrict__ rowStart, const int* __restrict__ hist,
                               const float* __restrict__ bias, float* __restrict__ out) {
    int w = __builtin_amdgcn_readfirstlane((int)(threadIdx.x >> 6));
    int node = blockIdx.x * 4 + w;
    int lane = threadIdx.x & 63;
    int q = lane >> 3, sl = lane & 7;
    int s0 = __builtin_amdgcn_readfirstlane(rowStart[node]);
    int cnt = __builtin_amdgcn_readfirstlane(hist[node]);
    float a0 = 0.f, a1 = 0.f, a2 = 0.f, a3 = 0.f, a4 = 0.f, a5 = 0.f, a6 = 0.f, a7 = 0.f;
    int i = 0;
    for (; i + 16 <= cnt; i += 16) {
        int sA = sortedSrc[s0 + i + q];
        int sB = sortedSrc[s0 + i + 8 + q];
        uint4 vA = g_l4[(size_t)sA * 8 + sl];
        uint4 vB = g_l4[(size_t)sB * 8 + sl];
        a0 += bflo(vA.x) + bflo(vB.x); a1 += bfhi(vA.x) + bfhi(vB.x);
        a2 += bflo(vA.y) + bflo(vB.y); a3 += bfhi(vA.y) + bfhi(vB.y);
        a4 += bflo(vA.z) + bflo(vB.z); a5 += bfhi(vA.z) + bfhi(vB.z);
        a6 += bflo(vA.w) + bflo(vB.w); a7 += bfhi(vA.w) + bfhi(vB.w);
    }
    for (; i + 8 <= cnt; i += 8) {
        int s = sortedSrc[s0 + i + q];
        uint4 v = g_l4[(size_t)s * 8 + sl];
        a0 += bflo(v.x); a1 += bfhi(v.x); a2 += bflo(v.y); a3 += bfhi(v.y);
        a4 += bflo(v.z); a5 += bfhi(v.z); a6 += bflo(v.w); a7 += bfhi(v.w);
    }
    if (q < cnt - i) {
        int s = sortedSrc[s0 + i + q];
        uint4 v = g_l4[(size_t)s * 8 + sl];
        a0 += bflo(v.x); a1 += bfhi(v.x); a2 += bflo(v.y); a3 += bfhi(v.y);
        a4 += bflo(v.z); a5 += bfhi(v.z); a6 += bflo(v.w); a7 += bfhi(v.w);
    }
    a0 += __shfl_xor(a0, 8, 64); a0 += __shfl_xor(a0, 16, 64); a0 += __shfl_xor(a0, 32, 64);
    a1 += __shfl_xor(a1, 8, 64); a1 += __shfl_xor(a1, 16, 64); a1 += __shfl_xor(a1, 32, 64);
    a2 += __shfl_xor(a2, 8, 64); a2 += __shfl_xor(a2, 16, 64); a2 += __shfl_xor(a2, 32, 64);
    a3 += __shfl_xor(a3, 8, 64); a3 += __shfl_xor(a3, 16, 64); a3 += __shfl_xor(a3, 32, 64);
    a4 += __shfl_xor(a4, 8, 64); a4 += __shfl_xor(a4, 16, 64); a4 += __shfl_xor(a4, 32, 64);
    a5 += __shfl_xor(a5, 8, 64); a5 += __shfl_xor(a5, 16, 64); a5 += __shfl_xor(a5, 32, 64);
    a6 += __shfl_xor(a6, 8, 64); a6 += __shfl_xor(a6, 16, 64); a6 += __shfl_xor(a6, 32, 64);
    a7 += __shfl_xor(a7, 8, 64); a7 += __shfl_xor(a7, 16, 64); a7 += __shfl_xor(a7, 32, 64);

    float dinv = 1.0f / fmaxf((float)cnt, 1.0f);
    uint4 gr = g_r4[(size_t)node * 8 + sl];
    bool valid = (sl < 5);  // cols sl*8..sl*8+7 < 40 iff sl<5 (pad cols are exact zeros)
    float b0 = 0, b1 = 0, b2 = 0, b3 = 0, b4 = 0, b5 = 0, b6 = 0, b7 = 0;
    if (valid) {
        b0 = bias[sl * 8 + 0]; b1 = bias[sl * 8 + 1]; b2 = bias[sl * 8 + 2]; b3 = bias[sl * 8 + 3];
        b4 = bias[sl * 8 + 4]; b5 = bias[sl * 8 + 5]; b6 = bias[sl * 8 + 6]; b7 = bias[sl * 8 + 7];
    }
    float t0 = a0 * dinv + bflo(gr.x) + b0;
    float t1 = a1 * dinv + bfhi(gr.x) + b1;
    float t2 = a2 * dinv + bflo(gr.y) + b2;
    float t3 = a3 * dinv + bfhi(gr.y) + b3;
    float t4 = a4 * dinv + bflo(gr.z) + b4;
    float t5 = a5 * dinv + bfhi(gr.z) + b5;
    float t6 = a6 * dinv + bflo(gr.w) + b6;
    float t7 = a7 * dinv + bfhi(gr.w) + b7;
    float ssq = t0 * t0 + t1 * t1 + t2 * t2 + t3 * t3 + t4 * t4 + t5 * t5 + t6 * t6 + t7 * t7;
    ssq += __shfl_xor(ssq, 1, 64); ssq += __shfl_xor(ssq, 2, 64); ssq += __shfl_xor(ssq, 4, 64);
    float inv = 1.0f / fmaxf(sqrtf(ssq), EPSN);
    float v0 = t0 * inv, v1 = t1 * inv, v2 = t2 * inv, v3 = t3 * inv;
    float v4 = t4 * inv, v5 = t5 * inv, v6 = t6 * inv, v7 = t7 * inv;
    float m = valid ? fmaxf(fmaxf(fmaxf(v0, v1), fmaxf(v2, v3)),
                            fmaxf(fmaxf(v4, v5), fmaxf(v6, v7))) : -INFINITY;
    m = fmaxf(m, __shfl_xor(m, 1, 64));
    m = fmaxf(m, __shfl_xor(m, 2, 64));
    m = fmaxf(m, __shfl_xor(m, 4, 64));
    float se = 0.0f;
    if (valid) {
        se = expf(v0 - m) + expf(v1 - m) + expf(v2 - m) + expf(v3 - m) +
             expf(v4 - m) + expf(v5 - m) + expf(v6 - m) + expf(v7 - m);
    }
    se += __shfl_xor(se, 1, 64); se += __shfl_xor(se, 2, 64); se += __shfl_xor(se, 4, 64);
    float ls = logf(se) + m;
    if (q == 0 && valid) {
        float* o = out + (size_t)node * D_OUT + sl * 8;
        ((float4*)o)[0] = (float4){v0 - ls, v1 - ls, v2 - ls, v3 - ls};
        ((float4*)o)[1] = (float4){v4 - ls, v5 - ls, v6 - ls, v7 - ls};
    }
}

static inline size_t align256(size_t x) { return (x + 255) & ~(size_t)255; }

extern "C" void kernel_launch(void* const* d_in, const int* in_sizes, int n_in,
                              void* d_out, int out_size, void* d_ws, size_t ws_size,
                              hipStream_t stream) {
    const float* x   = (const float*)d_in[0];
    const int*   ei  = (const int*)d_in[1];
    const float* Wl1 = (const float*)d_in[2];
    const float* bl1 = (const float*)d_in[3];
    const float* Wr1 = (const float*)d_in[4];
    const float* Wl2 = (const float*)d_in[5];
    const float* bl2 = (const float*)d_in[6];
    const float* Wr2 = (const float*)d_in[7];
    float* out = (float*)d_out;

    const int* src = ei;
    const int* dst = ei + N_EDGES;

    char* ws = (char*)d_ws;
    size_t off = 0;
    int* bucketCount = (int*)(ws + off); off += align256((size_t)NBUCK * 4);
    int* bucketStart = (int*)(ws + off); off += align256((size_t)(NBUCK + 1) * 4);
    int* cursor      = (int*)(ws + off); off += align256((size_t)NBUCK * 4);
    int* hist        = (int*)(ws + off); off += align256((size_t)N_NODES * 4);
    int* rowStart    = (int*)(ws + off); off += align256((size_t)N_NODES * 4);
    unsigned* pairs  = (unsigned*)(ws + off); off += align256((size_t)N_EDGES * 4);
    int* sortedSrc   = (int*)(ws + off); off += align256((size_t)N_EDGES * 4);
    unsigned* xb     = (unsigned*)(ws + off); off += align256((size_t)N_NODES * 128 * 2);
    unsigned* meanb  = (unsigned*)(ws + off); off += align256((size_t)N_NODES * 128 * 2);
    unsigned short* g_l = (unsigned short*)(ws + off); off += align256((size_t)N_NODES * 64 * 2);
    unsigned short* g_r = (unsigned short*)(ws + off); off += align256((size_t)N_NODES * 64 * 2);
    unsigned short* bswz1 = (unsigned short*)(ws + off); off += align256((size_t)SWZ1_TOTAL * 2);
    unsigned short* bswz2 = (unsigned short*)(ws + off); off += align256((size_t)SWZ2_TOTAL * 2);

    hipMemsetAsync(bucketCount, 0, (size_t)NBUCK * 4, stream);

    prep_kernel<<<NPART + CASTB + SWZB, 256, 0, stream>>>(
        dst, bucketCount, x, xb, Wl1, Wr1, Wl2, Wr2, bswz1, bswz2);
    bscan_kernel<<<1, 256, 0, stream>>>(bucketCount, bucketStart, cursor);
    bpart_kernel<<<PNPART, 512, 0, stream>>>(src, dst, cursor, pairs);
    csr_kernel<<<NBUCK, 256, 0, stream>>>(pairs, bucketStart, hist, rowStart, sortedSrc);

    agg_kernel<<<N_NODES / 4, 256, 0, stream>>>((const uint4*)xb, sortedSrc, rowStart, hist,
                                                (uint4*)meanb);
    gemm1g_kernel<<<(N_NODES + 63) / 64, 256, 0, stream>>>(
        (const unsigned short*)meanb, (const unsigned short*)xb,
        (const short*)bswz1, bl1, (const short*)bswz2, g_l, g_r);
    fused2g_kernel<<<N_NODES / 4, 256, 0, stream>>>(
        (const uint4*)g_l, (const uint4*)g_r, sortedSrc, rowStart, hist, bl2, out);
}

// Round 8
// 304.722 us; speedup vs baseline: 1.1088x; 1.0390x over previous
//
#include <hip/hip_runtime.h>
#include <math.h>

#define N_NODES 100000
#define N_EDGES 1600000
#define D_IN 128
#define HIDDEN 128
#define D_OUT 40
#define EPSN 1e-12f

// bucket = dst >> 8 (256 nodes per bucket)
#define NBUCK 391                            // ceil(100000/256)
#define EPB 4096                             // edges per bhist block
#define NPART ((N_EDGES + EPB - 1) / EPB)    // 391
#define PEPB 16384                           // edges per bpart block
#define PNPART ((N_EDGES + PEPB - 1) / PEPB) // 98

#define SWZ1_TOTAL (8 * 8 * 4 * 16 * 8)   // 32768  (K=256, N=128)
#define SWZ2_TOTAL (4 * 8 * 4 * 16 * 8)   // 16384  (K=128, N=128: [g_l64|g_r64])
#define CASTB ((N_NODES * 16) / 256)      // 6250 blocks, 1 uint4 per thread
#define SWZB ((SWZ1_TOTAL + SWZ2_TOTAL + 255) / 256)  // 192

typedef __attribute__((ext_vector_type(8))) short short8;
typedef __attribute__((ext_vector_type(4))) float float4v;

static __device__ inline unsigned short f2bf(float f) {
    union { float f; unsigned u; } v; v.f = f;
    unsigned r = v.u + 0x7fffu + ((v.u >> 16) & 1u);
    return (unsigned short)(r >> 16);
}
static __device__ inline float bflo(unsigned u) {
    union { unsigned u; float f; } v; v.u = u << 16;
    return v.f;
}
static __device__ inline float bfhi(unsigned u) {
    union { unsigned u; float f; } v; v.u = u & 0xffff0000u;
    return v.f;
}

// ---------------- prep: bhist + cast + both weight swizzles, fused ----------------
__global__ void prep_kernel(const int* __restrict__ dst, int* __restrict__ bucketCount,
                            const float* __restrict__ x, unsigned* __restrict__ xb,
                            const float* __restrict__ Wl1, const float* __restrict__ Wr1,
                            const float* __restrict__ Wl2, const float* __restrict__ Wr2,
                            unsigned short* __restrict__ out1, unsigned short* __restrict__ out2) {
    __shared__ int h[NBUCK];
    int b = blockIdx.x, t = threadIdx.x;
    if (b < NPART) {
        for (int i = t; i < NBUCK; i += 256) h[i] = 0;
        __syncthreads();
        int es = b * EPB;
        int ee = min(es + EPB, N_EDGES);
        for (int i = es + t; i < ee; i += 256) atomicAdd(&h[dst[i] >> 8], 1);
        __syncthreads();
        for (int i = t; i < NBUCK; i += 256)
            if (h[i]) atomicAdd(&bucketCount[i], h[i]);
        return;
    }
    b -= NPART;
    if (b < CASTB) {
        int g = b * 256 + t;
        const float4* x4 = (const float4*)x;
        float4 lo = x4[2 * g], hi = x4[2 * g + 1];
        uint4 o;
        o.x = (unsigned)f2bf(lo.x) | ((unsigned)f2bf(lo.y) << 16);
        o.y = (unsigned)f2bf(lo.z) | ((unsigned)f2bf(lo.w) << 16);
        o.z = (unsigned)f2bf(hi.x) | ((unsigned)f2bf(hi.y) << 16);
        o.w = (unsigned)f2bf(hi.z) | ((unsigned)f2bf(hi.w) << 16);
        ((uint4*)xb)[g] = o;
        return;
    }
    b -= CASTB;
    {
        int idx = b * 256 + t;
        if (idx < SWZ1_TOTAL) {
            // layer-1 weights: W_cat=[Wl1;Wr1], K=256, N=128
            int j = idx & 7, l15 = (idx >> 3) & 15, quad = (idx >> 7) & 3;
            int rem = idx >> 9;
            int c = rem & 7, kt = rem >> 3;
            int k = kt * 32 + quad * 8 + j;
            int n = c * 16 + l15;
            float val = (k < 128) ? Wl1[k * HIDDEN + n] : Wr1[(k - 128) * HIDDEN + n];
            out1[idx] = f2bf(val);
        } else if (idx < SWZ1_TOTAL + SWZ2_TOTAL) {
            // layer-2 combined: K=128, N=128 cols: [0..39]=Wl2, [64..103]=Wr2, rest 0
            idx -= SWZ1_TOTAL;
            int j = idx & 7, l15 = (idx >> 3) & 15, quad = (idx >> 7) & 3;
            int rem = idx >> 9;
            int c = rem & 7, kt = rem >> 3;
            int k = kt * 32 + quad * 8 + j;
            int n = c * 16 + l15;
            float val = 0.0f;
            if (n < D_OUT) val = Wl2[k * D_OUT + n];
            else if (n >= 64 && n < 64 + D_OUT) val = Wr2[k * D_OUT + (n - 64)];
            out2[idx] = f2bf(val);
        }
    }
}

// ---------------- scan 391 bucket counts (one block) ----------------
__global__ void bscan_kernel(const int* __restrict__ bc, int* __restrict__ bstart,
                             int* __restrict__ cursor) {
    __shared__ int s[256];
    int t = threadIdx.x;
    int a = (2 * t < NBUCK) ? bc[2 * t] : 0;
    int b = (2 * t + 1 < NBUCK) ? bc[2 * t + 1] : 0;
    int tp = a + b;
    s[t] = tp;
    __syncthreads();
    for (int off = 1; off < 256; off <<= 1) {
        int tmp = (t >= off) ? s[t - off] : 0;
        __syncthreads();
        s[t] += tmp;
        __syncthreads();
    }
    int texcl = s[t] - tp;
    if (2 * t < NBUCK) { bstart[2 * t] = texcl; cursor[2 * t] = texcl; }
    if (2 * t + 1 < NBUCK) { bstart[2 * t + 1] = texcl + a; cursor[2 * t + 1] = texcl + a; }
    if (t == 255) bstart[NBUCK] = s[255];
}

// ---------------- partition edges into buckets (packed u32), long runs ----------------
__global__ __launch_bounds__(512) void bpart_kernel(
    const int* __restrict__ src, const int* __restrict__ dst,
    int* __restrict__ cursor, unsigned* __restrict__ pairs) {
    __shared__ int h[NBUCK];
    __shared__ int base[NBUCK];
    int t = threadIdx.x;
    for (int i = t; i < NBUCK; i += 512) h[i] = 0;
    __syncthreads();
    int es = blockIdx.x * PEPB;
    int ee = min(es + PEPB, N_EDGES);
    for (int i = es + t; i < ee; i += 512) atomicAdd(&h[dst[i] >> 8], 1);
    __syncthreads();
    for (int i = t; i < NBUCK; i += 512) {
        int c = h[i];
        base[i] = c ? atomicAdd(&cursor[i], c) : 0;
    }
    __syncthreads();
    for (int i = t; i < NBUCK; i += 512) h[i] = 0;
    __syncthreads();
    for (int i = es + t; i < ee; i += 512) {
        int d = dst[i];
        int bk = d >> 8;
        int r = atomicAdd(&h[bk], 1);
        pairs[base[bk] + r] = ((unsigned)src[i] << 8) | (unsigned)(d & 255);
    }
}

// ---------------- per-bucket CSR finalize: count+scan+fill all in LDS ----------------
__global__ void csr_kernel(const unsigned* __restrict__ pairs, const int* __restrict__ bstart,
                           int* __restrict__ hist, int* __restrict__ rowStart,
                           int* __restrict__ sortedSrc) {
    __shared__ int cnt[256];
    __shared__ int sc[256];
    __shared__ int cur[256];
    int b = blockIdx.x, t = threadIdx.x;
    int es = bstart[b], ee = bstart[b + 1];
    cnt[t] = 0;
    __syncthreads();
    for (int i = es + t; i < ee; i += 256) atomicAdd(&cnt[pairs[i] & 255], 1);
    __syncthreads();
    int v = cnt[t];
    sc[t] = v;
    __syncthreads();
    for (int off = 1; off < 256; off <<= 1) {
        int tmp = (t >= off) ? sc[t - off] : 0;
        __syncthreads();
        sc[t] += tmp;
        __syncthreads();
    }
    int excl = sc[t] - v;
    int node = (b << 8) + t;
    if (node < N_NODES) {
        hist[node] = v;
        rowStart[node] = es + excl;
    }
    cur[t] = excl;
    __syncthreads();
    for (int i = es + t; i < ee; i += 256) {
        unsigned p = pairs[i];
        int r = atomicAdd(&cur[p & 255], 1);
        sortedSrc[es + r] = (int)(p >> 8);
    }
}

// ---------------- layer-1 gather-mean: one wave per node, dwordx4, 8 edges/iter ----------------
__global__ void agg_kernel(const uint4* __restrict__ feat,  // [N][16] uint4 (256B rows)
                           const int* __restrict__ sortedSrc,
                           const int* __restrict__ rowStart, const int* __restrict__ hist,
                           uint4* __restrict__ meanb) {
    int w = __builtin_amdgcn_readfirstlane((int)(threadIdx.x >> 6));
    int node = blockIdx.x * 4 + w;
    int lane = threadIdx.x & 63;
    int q = lane >> 4, sl = lane & 15;
    int s0 = __builtin_amdgcn_readfirstlane(rowStart[node]);
    int cnt = __builtin_amdgcn_readfirstlane(hist[node]);
    float a0 = 0.f, a1 = 0.f, a2 = 0.f, a3 = 0.f, a4 = 0.f, a5 = 0.f, a6 = 0.f, a7 = 0.f;
    int i = 0;
    for (; i + 8 <= cnt; i += 8) {
        int sA = sortedSrc[s0 + i + q];
        int sB = sortedSrc[s0 + i + 4 + q];
        uint4 vA = feat[(size_t)sA * 16 + sl];
        uint4 vB = feat[(size_t)sB * 16 + sl];
        a0 += bflo(vA.x) + bflo(vB.x); a1 += bfhi(vA.x) + bfhi(vB.x);
        a2 += bflo(vA.y) + bflo(vB.y); a3 += bfhi(vA.y) + bfhi(vB.y);
        a4 += bflo(vA.z) + bflo(vB.z); a5 += bfhi(vA.z) + bfhi(vB.z);
        a6 += bflo(vA.w) + bflo(vB.w); a7 += bfhi(vA.w) + bfhi(vB.w);
    }
    for (; i + 4 <= cnt; i += 4) {
        int s = sortedSrc[s0 + i + q];
        uint4 v = feat[(size_t)s * 16 + sl];
        a0 += bflo(v.x); a1 += bfhi(v.x); a2 += bflo(v.y); a3 += bfhi(v.y);
        a4 += bflo(v.z); a5 += bfhi(v.z); a6 += bflo(v.w); a7 += bfhi(v.w);
    }
    if (q < cnt - i) {
        int s = sortedSrc[s0 + i + q];
        uint4 v = feat[(size_t)s * 16 + sl];
        a0 += bflo(v.x); a1 += bfhi(v.x); a2 += bflo(v.y); a3 += bfhi(v.y);
        a4 += bflo(v.z); a5 += bfhi(v.z); a6 += bflo(v.w); a7 += bfhi(v.w);
    }
    a0 += __shfl_xor(a0, 16, 64); a0 += __shfl_xor(a0, 32, 64);
    a1 += __shfl_xor(a1, 16, 64); a1 += __shfl_xor(a1, 32, 64);
    a2 += __shfl_xor(a2, 16, 64); a2 += __shfl_xor(a2, 32, 64);
    a3 += __shfl_xor(a3, 16, 64); a3 += __shfl_xor(a3, 32, 64);
    a4 += __shfl_xor(a4, 16, 64); a4 += __shfl_xor(a4, 32, 64);
    a5 += __shfl_xor(a5, 16, 64); a5 += __shfl_xor(a5, 32, 64);
    a6 += __shfl_xor(a6, 16, 64); a6 += __shfl_xor(a6, 32, 64);
    a7 += __shfl_xor(a7, 16, 64); a7 += __shfl_xor(a7, 32, 64);
    if (q == 0) {
        float dinv = 1.0f / fmaxf((float)cnt, 1.0f);
        uint4 o;
        o.x = (unsigned)f2bf(a0 * dinv) | ((unsigned)f2bf(a1 * dinv) << 16);
        o.y = (unsigned)f2bf(a2 * dinv) | ((unsigned)f2bf(a3 * dinv) << 16);
        o.z = (unsigned)f2bf(a4 * dinv) | ((unsigned)f2bf(a5 * dinv) << 16);
        o.w = (unsigned)f2bf(a6 * dinv) | ((unsigned)f2bf(a7 * dinv) << 16);
        meanb[(size_t)node * 16 + sl] = o;
    }
}

// ---------------- layer-1 GEMM + norm + relu + layer-2 projection (2 MFMA passes) ----------------
__global__ __launch_bounds__(256) void gemm1g_kernel(
    const unsigned short* __restrict__ meanb, const unsigned short* __restrict__ xb,
    const short* __restrict__ bswz1, const float* __restrict__ bias1,
    const short* __restrict__ bswz2,
    unsigned short* __restrict__ g_l, unsigned short* __restrict__ g_r) {
    __shared__ unsigned short hT[4][16][140];
    int tid = threadIdx.x;
    int w = __builtin_amdgcn_readfirstlane(tid >> 6);
    int lane = tid & 63;
    int l15 = lane & 15, quad = lane >> 4;
    int n0 = blockIdx.x * 64;
    int nodeA = n0 + w * 16 + l15;
    if (nodeA >= N_NODES) nodeA = N_NODES - 1;

    float4v acc[8];
#pragma unroll
    for (int c = 0; c < 8; c++) acc[c] = (float4v){0.f, 0.f, 0.f, 0.f};
#pragma unroll
    for (int kt = 0; kt < 8; kt++) {
        const unsigned short* ab = (kt < 4) ? meanb : xb;
        short8 a = *(const short8*)(ab + (size_t)nodeA * 128 + (kt & 3) * 32 + quad * 8);
#pragma unroll
        for (int c = 0; c < 8; c++) {
            short8 b = *(const short8*)(bswz1 + (((kt * 8 + c) * 4 + quad) * 16 + l15) * 8);
            acc[c] = __builtin_amdgcn_mfma_f32_16x16x32_bf16(a, b, acc[c], 0, 0, 0);
        }
    }

    float v[8][4];
    float ss[4] = {0.f, 0.f, 0.f, 0.f};
#pragma unroll
    for (int c = 0; c < 8; c++) {
        float bi = bias1[c * 16 + l15];
#pragma unroll
        for (int r = 0; r < 4; r++) {
            float t = acc[c][r] + bi;
            v[c][r] = t;
            ss[r] += t * t;
        }
    }
#pragma unroll
    for (int r = 0; r < 4; r++)
        for (int off = 1; off < 16; off <<= 1) ss[r] += __shfl_xor(ss[r], off, 64);
#pragma unroll
    for (int r = 0; r < 4; r++) {
        float inv = 1.0f / fmaxf(sqrtf(ss[r]), EPSN);
#pragma unroll
        for (int c = 0; c < 8; c++) {
            hT[w][quad * 4 + r][c * 16 + l15] = f2bf(fmaxf(v[c][r] * inv, 0.0f));
        }
    }

    float4v acc2[8];
#pragma unroll
    for (int c = 0; c < 8; c++) acc2[c] = (float4v){0.f, 0.f, 0.f, 0.f};
#pragma unroll
    for (int kt = 0; kt < 4; kt++) {
        short8 a = *(const short8*)&hT[w][l15][kt * 32 + quad * 8];
#pragma unroll
        for (int c = 0; c < 8; c++) {
            short8 b = *(const short8*)(bswz2 + (((kt * 8 + c) * 4 + quad) * 16 + l15) * 8);
            acc2[c] = __builtin_amdgcn_mfma_f32_16x16x32_bf16(a, b, acc2[c], 0, 0, 0);
        }
    }
#pragma unroll
    for (int r = 0; r < 4; r++) {
        int node = n0 + w * 16 + quad * 4 + r;
        if (node < N_NODES) {
#pragma unroll
            for (int c = 0; c < 4; c++)
                g_l[(size_t)node * 64 + c * 16 + l15] = f2bf(acc2[c][r]);
#pragma unroll
            for (int c = 4; c < 8; c++)
                g_r[(size_t)node * 64 + (c - 4) * 16 + l15] = f2bf(acc2[c][r]);
        }
    }
}

// ---------------- layer 2 final: 4 nodes per wave ----------------
// Lane layout: g = lane>>4 (node within wave), q1 = (lane>>3)&1 (edge group),
// sl = lane&7 (uint4 column of the 128B g_l row).
__global__ void fused2h_kernel(const uint4* __restrict__ g_l4, const uint4* __restrict__ g_r4,
                               const int* __restrict__ sortedSrc,
                               const int* __restrict__ rowStart, const int* __restrict__ hist,
                               const float* __restrict__ bias, float* __restrict__ out) {
    int tid = threadIdx.x;
    int w = __builtin_amdgcn_readfirstlane(tid >> 6);
    int lane = tid & 63;
    int g = lane >> 4, q1 = (lane >> 3) & 1, sl = lane & 7;
    int node = blockIdx.x * 16 + w * 4 + g;   // N_NODES % 16 == 0
    int s0 = rowStart[node];
    int cnt = hist[node];
    float a0 = 0.f, a1 = 0.f, a2 = 0.f, a3 = 0.f, a4 = 0.f, a5 = 0.f, a6 = 0.f, a7 = 0.f;
    int i = 0;
    for (; i + 4 <= cnt; i += 4) {
        int sA = sortedSrc[s0 + i + q1];
        int sB = sortedSrc[s0 + i + 2 + q1];
        uint4 vA = g_l4[(size_t)sA * 8 + sl];
        uint4 vB = g_l4[(size_t)sB * 8 + sl];
        a0 += bflo(vA.x) + bflo(vB.x); a1 += bfhi(vA.x) + bfhi(vB.x);
        a2 += bflo(vA.y) + bflo(vB.y); a3 += bfhi(vA.y) + bfhi(vB.y);
        a4 += bflo(vA.z) + bflo(vB.z); a5 += bfhi(vA.z) + bfhi(vB.z);
        a6 += bflo(vA.w) + bflo(vB.w); a7 += bfhi(vA.w) + bfhi(vB.w);
    }
    if (i + q1 < cnt) {
        int s = sortedSrc[s0 + i + q1];
        uint4 v = g_l4[(size_t)s * 8 + sl];
        a0 += bflo(v.x); a1 += bfhi(v.x); a2 += bflo(v.y); a3 += bfhi(v.y);
        a4 += bflo(v.z); a5 += bfhi(v.z); a6 += bflo(v.w); a7 += bfhi(v.w);
    }
    i += 2;
    if (i + q1 < cnt) {
        int s = sortedSrc[s0 + i + q1];
        uint4 v = g_l4[(size_t)s * 8 + sl];
        a0 += bflo(v.x); a1 += bfhi(v.x); a2 += bflo(v.y); a3 += bfhi(v.y);
        a4 += bflo(v.z); a5 += bfhi(v.z); a6 += bflo(v.w); a7 += bfhi(v.w);
    }
    // combine the two edge-groups (lanes differing in bit 3)
    a0 += __shfl_xor(a0, 8, 64);
    a1 += __shfl_xor(a1, 8, 64);
    a2 += __shfl_xor(a2, 8, 64);
    a3 += __shfl_xor(a3, 8, 64);
    a4 += __shfl_xor(a4, 8, 64);
    a5 += __shfl_xor(a5, 8, 64);
    a6 += __shfl_xor(a6, 8, 64);
    a7 += __shfl_xor(a7, 8, 64);
    // both q1 halves now hold full sums; compute epilogue redundantly, reduce over sl (xor 1,2,4)
    float dinv = 1.0f / fmaxf((float)cnt, 1.0f);
    uint4 gr = g_r4[(size_t)node * 8 + sl];
    bool valid = (sl < 5);  // cols sl*8..sl*8+7 < 40 iff sl<5 (pad cols are exact zeros)
    float b0 = 0, b1 = 0, b2 = 0, b3 = 0, b4 = 0, b5 = 0, b6 = 0, b7 = 0;
    if (valid) {
        b0 = bias[sl * 8 + 0]; b1 = bias[sl * 8 + 1]; b2 = bias[sl * 8 + 2]; b3 = bias[sl * 8 + 3];
        b4 = bias[sl * 8 + 4]; b5 = bias[sl * 8 + 5]; b6 = bias[sl * 8 + 6]; b7 = bias[sl * 8 + 7];
    }
    float t0 = a0 * dinv + bflo(gr.x) + b0;
    float t1 = a1 * dinv + bfhi(gr.x) + b1;
    float t2 = a2 * dinv + bflo(gr.y) + b2;
    float t3 = a3 * dinv + bfhi(gr.y) + b3;
    float t4 = a4 * dinv + bflo(gr.z) + b4;
    float t5 = a5 * dinv + bfhi(gr.z) + b5;
    float t6 = a6 * dinv + bflo(gr.w) + b6;
    float t7 = a7 * dinv + bfhi(gr.w) + b7;
    float ssq = t0 * t0 + t1 * t1 + t2 * t2 + t3 * t3 + t4 * t4 + t5 * t5 + t6 * t6 + t7 * t7;
    ssq += __shfl_xor(ssq, 1, 64); ssq += __shfl_xor(ssq, 2, 64); ssq += __shfl_xor(ssq, 4, 64);
    float inv = 1.0f / fmaxf(sqrtf(ssq), EPSN);
    float v0 = t0 * inv, v1 = t1 * inv, v2 = t2 * inv, v3 = t3 * inv;
    float v4 = t4 * inv, v5 = t5 * inv, v6 = t6 * inv, v7 = t7 * inv;
    float m = valid ? fmaxf(fmaxf(fmaxf(v0, v1), fmaxf(v2, v3)),
                            fmaxf(fmaxf(v4, v5), fmaxf(v6, v7))) : -INFINITY;
    m = fmaxf(m, __shfl_xor(m, 1, 64));
    m = fmaxf(m, __shfl_xor(m, 2, 64));
    m = fmaxf(m, __shfl_xor(m, 4, 64));
    float se = 0.0f;
    if (valid) {
        se = expf(v0 - m) + expf(v1 - m) + expf(v2 - m) + expf(v3 - m) +
             expf(v4 - m) + expf(v5 - m) + expf(v6 - m) + expf(v7 - m);
    }
    se += __shfl_xor(se, 1, 64); se += __shfl_xor(se, 2, 64); se += __shfl_xor(se, 4, 64);
    float ls = logf(se) + m;
    if (q1 == 0 && valid) {
        float* o = out + (size_t)node * D_OUT + sl * 8;
        ((float4*)o)[0] = (float4){v0 - ls, v1 - ls, v2 - ls, v3 - ls};
        ((float4*)o)[1] = (float4){v4 - ls, v5 - ls, v6 - ls, v7 - ls};
    }
}

static inline size_t align256(size_t x) { return (x + 255) & ~(size_t)255; }

extern "C" void kernel_launch(void* const* d_in, const int* in_sizes, int n_in,
                              void* d_out, int out_size, void* d_ws, size_t ws_size,
                              hipStream_t stream) {
    const float* x   = (const float*)d_in[0];
    const int*   ei  = (const int*)d_in[1];
    const float* Wl1 = (const float*)d_in[2];
    const float* bl1 = (const float*)d_in[3];
    const float* Wr1 = (const float*)d_in[4];
    const float* Wl2 = (const float*)d_in[5];
    const float* bl2 = (const float*)d_in[6];
    const float* Wr2 = (const float*)d_in[7];
    float* out = (float*)d_out;

    const int* src = ei;
    const int* dst = ei + N_EDGES;

    char* ws = (char*)d_ws;
    size_t off = 0;
    int* bucketCount = (int*)(ws + off); off += align256((size_t)NBUCK * 4);
    int* bucketStart = (int*)(ws + off); off += align256((size_t)(NBUCK + 1) * 4);
    int* cursor      = (int*)(ws + off); off += align256((size_t)NBUCK * 4);
    int* hist        = (int*)(ws + off); off += align256((size_t)N_NODES * 4);
    int* rowStart    = (int*)(ws + off); off += align256((size_t)N_NODES * 4);
    unsigned* pairs  = (unsigned*)(ws + off); off += align256((size_t)N_EDGES * 4);
    int* sortedSrc   = (int*)(ws + off); off += align256((size_t)N_EDGES * 4);
    unsigned* xb     = (unsigned*)(ws + off); off += align256((size_t)N_NODES * 128 * 2);
    unsigned* meanb  = (unsigned*)(ws + off); off += align256((size_t)N_NODES * 128 * 2);
    unsigned short* g_l = (unsigned short*)(ws + off); off += align256((size_t)N_NODES * 64 * 2);
    unsigned short* g_r = (unsigned short*)(ws + off); off += align256((size_t)N_NODES * 64 * 2);
    unsigned short* bswz1 = (unsigned short*)(ws + off); off += align256((size_t)SWZ1_TOTAL * 2);
    unsigned short* bswz2 = (unsigned short*)(ws + off); off += align256((size_t)SWZ2_TOTAL * 2);

    hipMemsetAsync(bucketCount, 0, (size_t)NBUCK * 4, stream);

    prep_kernel<<<NPART + CASTB + SWZB, 256, 0, stream>>>(
        dst, bucketCount, x, xb, Wl1, Wr1, Wl2, Wr2, bswz1, bswz2);
    bscan_kernel<<<1, 256, 0, stream>>>(bucketCount, bucketStart, cursor);
    bpart_kernel<<<PNPART, 512, 0, stream>>>(src, dst, cursor, pairs);
    csr_kernel<<<NBUCK, 256, 0, stream>>>(pairs, bucketStart, hist, rowStart, sortedSrc);

    agg_kernel<<<N_NODES / 4, 256, 0, stream>>>((const uint4*)xb, sortedSrc, rowStart, hist,
                                                (uint4*)meanb);
    gemm1g_kernel<<<(N_NODES + 63) / 64, 256, 0, stream>>>(
        (const unsigned short*)meanb, (const unsigned short*)xb,
        (const short*)bswz1, bl1, (const short*)bswz2, g_l, g_r);
    fused2h_kernel<<<N_NODES / 16, 256, 0, stream>>>(
        (const uint4*)g_l, (const uint4*)g_r, sortedSrc, rowStart, hist, bl2, out);
}

// Round 9
// 303.754 us; speedup vs baseline: 1.1123x; 1.0032x over previous
//
#include <hip/hip_runtime.h>
#include <math.h>

#define N_NODES 100000
#define N_EDGES 1600000
#define D_IN 128
#define HIDDEN 128
#define D_OUT 40
#define EPSN 1e-12f

// bucket = dst >> 8 (256 nodes per bucket)
#define NBUCK 391                            // ceil(100000/256)
#define EPB 4096                             // edges per bhist block
#define NPART ((N_EDGES + EPB - 1) / EPB)    // 391
#define PEPB 16384                           // edges per bpart block
#define PNPART ((N_EDGES + PEPB - 1) / PEPB) // 98

#define SWZ1_TOTAL (8 * 8 * 4 * 16 * 8)   // 32768  (K=256, N=128)
#define SWZ2_TOTAL (4 * 8 * 4 * 16 * 8)   // 16384  (K=128, N=128: [g_l64|g_r64])
#define CASTB ((N_NODES * 16) / 256)      // 6250 blocks: fp32 -> bf16 (1 uint4/thread)
#define F8B ((N_NODES * 32) / 256)        // 12500 blocks: fp32 -> fp8 (1 u32/thread)
#define SWZB ((SWZ1_TOTAL + SWZ2_TOTAL + 255) / 256)  // 192

typedef __attribute__((ext_vector_type(8))) short short8;
typedef __attribute__((ext_vector_type(4))) float float4v;
typedef __attribute__((ext_vector_type(2))) float float2v;

static __device__ inline unsigned short f2bf(float f) {
    union { float f; unsigned u; } v; v.f = f;
    unsigned r = v.u + 0x7fffu + ((v.u >> 16) & 1u);
    return (unsigned short)(r >> 16);
}
static __device__ inline float bflo(unsigned u) {
    union { unsigned u; float f; } v; v.u = u << 16;
    return v.f;
}
static __device__ inline float bfhi(unsigned u) {
    union { unsigned u; float f; } v; v.u = u & 0xffff0000u;
    return v.f;
}

// ---------- fp8 e4m3 encode/decode: HW cvt when available, bit-trick fallback ----------
#if defined(__has_builtin)
#if __has_builtin(__builtin_amdgcn_cvt_pk_f32_fp8) && __has_builtin(__builtin_amdgcn_cvt_pk_fp8_f32)
#define HAVE_HW_FP8 1
#endif
#endif

static __device__ inline float2v fp8lo(unsigned u) {
#ifdef HAVE_HW_FP8
    return __builtin_amdgcn_cvt_pk_f32_fp8(u, false);
#else
    unsigned b0 = u & 0xffu, b1 = (u >> 8) & 0xffu;
    union { unsigned u; float f; } v0, v1;
    v0.u = ((b0 & 0x80u) << 24) | ((b0 & 0x7fu) << 20);
    v1.u = ((b1 & 0x80u) << 24) | ((b1 & 0x7fu) << 20);
    float2v r; r.x = v0.f * 0x1p+120f; r.y = v1.f * 0x1p+120f;
    return r;
#endif
}
static __device__ inline float2v fp8hi(unsigned u) {
#ifdef HAVE_HW_FP8
    return __builtin_amdgcn_cvt_pk_f32_fp8(u, true);
#else
    unsigned b0 = (u >> 16) & 0xffu, b1 = (u >> 24) & 0xffu;
    union { unsigned u; float f; } v0, v1;
    v0.u = ((b0 & 0x80u) << 24) | ((b0 & 0x7fu) << 20);
    v1.u = ((b1 & 0x80u) << 24) | ((b1 & 0x7fu) << 20);
    float2v r; r.x = v0.f * 0x1p+120f; r.y = v1.f * 0x1p+120f;
    return r;
#endif
}
#ifndef HAVE_HW_FP8
static __device__ inline unsigned enc1(float x) {
    union { float f; unsigned u; } v; v.f = x * 0x1p-120f;
    unsigned um = v.u & 0x7fffffffu;
    unsigned r = um + 0x7FFFFu + ((um >> 20) & 1u);
    return ((r >> 20) & 0x7fu) | ((v.u >> 24) & 0x80u);
}
#endif
static __device__ inline unsigned fp8pack(float f0, float f1, float f2, float f3) {
#ifdef HAVE_HW_FP8
    unsigned u = __builtin_amdgcn_cvt_pk_fp8_f32(f0, f1, 0u, false);
    u = __builtin_amdgcn_cvt_pk_fp8_f32(f2, f3, u, true);
    return u;
#else
    return enc1(f0) | (enc1(f1) << 8) | (enc1(f2) << 16) | (enc1(f3) << 24);
#endif
}

// ---------------- prep: bhist + bf16 cast + fp8 cast + weight swizzles, fused ----------------
__global__ void prep_kernel(const int* __restrict__ dst, int* __restrict__ bucketCount,
                            const float* __restrict__ x, unsigned* __restrict__ xb,
                            unsigned* __restrict__ xf8,
                            const float* __restrict__ Wl1, const float* __restrict__ Wr1,
                            const float* __restrict__ Wl2, const float* __restrict__ Wr2,
                            unsigned short* __restrict__ out1, unsigned short* __restrict__ out2) {
    __shared__ int h[NBUCK];
    int b = blockIdx.x, t = threadIdx.x;
    if (b < NPART) {
        for (int i = t; i < NBUCK; i += 256) h[i] = 0;
        __syncthreads();
        int es = b * EPB;
        int ee = min(es + EPB, N_EDGES);
        for (int i = es + t; i < ee; i += 256) atomicAdd(&h[dst[i] >> 8], 1);
        __syncthreads();
        for (int i = t; i < NBUCK; i += 256)
            if (h[i]) atomicAdd(&bucketCount[i], h[i]);
        return;
    }
    b -= NPART;
    if (b < CASTB) {
        int g = b * 256 + t;
        const float4* x4 = (const float4*)x;
        float4 lo = x4[2 * g], hi = x4[2 * g + 1];
        uint4 o;
        o.x = (unsigned)f2bf(lo.x) | ((unsigned)f2bf(lo.y) << 16);
        o.y = (unsigned)f2bf(lo.z) | ((unsigned)f2bf(lo.w) << 16);
        o.z = (unsigned)f2bf(hi.x) | ((unsigned)f2bf(hi.y) << 16);
        o.w = (unsigned)f2bf(hi.z) | ((unsigned)f2bf(hi.w) << 16);
        ((uint4*)xb)[g] = o;
        return;
    }
    b -= CASTB;
    if (b < F8B) {
        int g = b * 256 + t;
        float4 f = ((const float4*)x)[g];
        xf8[g] = fp8pack(f.x, f.y, f.z, f.w);
        return;
    }
    b -= F8B;
    {
        int idx = b * 256 + t;
        if (idx < SWZ1_TOTAL) {
            int j = idx & 7, l15 = (idx >> 3) & 15, quad = (idx >> 7) & 3;
            int rem = idx >> 9;
            int c = rem & 7, kt = rem >> 3;
            int k = kt * 32 + quad * 8 + j;
            int n = c * 16 + l15;
            float val = (k < 128) ? Wl1[k * HIDDEN + n] : Wr1[(k - 128) * HIDDEN + n];
            out1[idx] = f2bf(val);
        } else if (idx < SWZ1_TOTAL + SWZ2_TOTAL) {
            idx -= SWZ1_TOTAL;
            int j = idx & 7, l15 = (idx >> 3) & 15, quad = (idx >> 7) & 3;
            int rem = idx >> 9;
            int c = rem & 7, kt = rem >> 3;
            int k = kt * 32 + quad * 8 + j;
            int n = c * 16 + l15;
            float val = 0.0f;
            if (n < D_OUT) val = Wl2[k * D_OUT + n];
            else if (n >= 64 && n < 64 + D_OUT) val = Wr2[k * D_OUT + (n - 64)];
            out2[idx] = f2bf(val);
        }
    }
}

// ---------------- scan 391 bucket counts (one block) ----------------
__global__ void bscan_kernel(const int* __restrict__ bc, int* __restrict__ bstart,
                             int* __restrict__ cursor) {
    __shared__ int s[256];
    int t = threadIdx.x;
    int a = (2 * t < NBUCK) ? bc[2 * t] : 0;
    int b = (2 * t + 1 < NBUCK) ? bc[2 * t + 1] : 0;
    int tp = a + b;
    s[t] = tp;
    __syncthreads();
    for (int off = 1; off < 256; off <<= 1) {
        int tmp = (t >= off) ? s[t - off] : 0;
        __syncthreads();
        s[t] += tmp;
        __syncthreads();
    }
    int texcl = s[t] - tp;
    if (2 * t < NBUCK) { bstart[2 * t] = texcl; cursor[2 * t] = texcl; }
    if (2 * t + 1 < NBUCK) { bstart[2 * t + 1] = texcl + a; cursor[2 * t + 1] = texcl + a; }
    if (t == 255) bstart[NBUCK] = s[255];
}

// ---------------- partition edges into buckets (packed u32), long runs ----------------
__global__ __launch_bounds__(512) void bpart_kernel(
    const int* __restrict__ src, const int* __restrict__ dst,
    int* __restrict__ cursor, unsigned* __restrict__ pairs) {
    __shared__ int h[NBUCK];
    __shared__ int base[NBUCK];
    int t = threadIdx.x;
    for (int i = t; i < NBUCK; i += 512) h[i] = 0;
    __syncthreads();
    int es = blockIdx.x * PEPB;
    int ee = min(es + PEPB, N_EDGES);
    for (int i = es + t; i < ee; i += 512) atomicAdd(&h[dst[i] >> 8], 1);
    __syncthreads();
    for (int i = t; i < NBUCK; i += 512) {
        int c = h[i];
        base[i] = c ? atomicAdd(&cursor[i], c) : 0;
    }
    __syncthreads();
    for (int i = t; i < NBUCK; i += 512) h[i] = 0;
    __syncthreads();
    for (int i = es + t; i < ee; i += 512) {
        int d = dst[i];
        int bk = d >> 8;
        int r = atomicAdd(&h[bk], 1);
        pairs[base[bk] + r] = ((unsigned)src[i] << 8) | (unsigned)(d & 255);
    }
}

// ---------------- per-bucket CSR finalize: count+scan+fill all in LDS ----------------
__global__ void csr_kernel(const unsigned* __restrict__ pairs, const int* __restrict__ bstart,
                           int* __restrict__ hist, int* __restrict__ rowStart,
                           int* __restrict__ sortedSrc) {
    __shared__ int cnt[256];
    __shared__ int sc[256];
    __shared__ int cur[256];
    int b = blockIdx.x, t = threadIdx.x;
    int es = bstart[b], ee = bstart[b + 1];
    cnt[t] = 0;
    __syncthreads();
    for (int i = es + t; i < ee; i += 256) atomicAdd(&cnt[pairs[i] & 255], 1);
    __syncthreads();
    int v = cnt[t];
    sc[t] = v;
    __syncthreads();
    for (int off = 1; off < 256; off <<= 1) {
        int tmp = (t >= off) ? sc[t - off] : 0;
        __syncthreads();
        sc[t] += tmp;
        __syncthreads();
    }
    int excl = sc[t] - v;
    int node = (b << 8) + t;
    if (node < N_NODES) {
        hist[node] = v;
        rowStart[node] = es + excl;
    }
    cur[t] = excl;
    __syncthreads();
    for (int i = es + t; i < ee; i += 256) {
        unsigned p = pairs[i];
        int r = atomicAdd(&cur[p & 255], 1);
        sortedSrc[es + r] = (int)(p >> 8);
    }
}

// ---------------- layer-1 gather-mean from fp8 table: one wave per node ----------------
// 8 lanes (sl) x 16B cover the 128B fp8 row; 8 edge-groups (q); 16 accumulators/lane.
#define ACC4(v)                                                                   \
    { float2v p;                                                                  \
      p = fp8lo(v.x); a[0] += p.x; a[1] += p.y;                                   \
      p = fp8hi(v.x); a[2] += p.x; a[3] += p.y;                                   \
      p = fp8lo(v.y); a[4] += p.x; a[5] += p.y;                                   \
      p = fp8hi(v.y); a[6] += p.x; a[7] += p.y;                                   \
      p = fp8lo(v.z); a[8] += p.x; a[9] += p.y;                                   \
      p = fp8hi(v.z); a[10] += p.x; a[11] += p.y;                                 \
      p = fp8lo(v.w); a[12] += p.x; a[13] += p.y;                                 \
      p = fp8hi(v.w); a[14] += p.x; a[15] += p.y; }

__global__ void agg_kernel(const uint4* __restrict__ xf8,  // [N][8] uint4 (128B fp8 rows)
                           const int* __restrict__ sortedSrc,
                           const int* __restrict__ rowStart, const int* __restrict__ hist,
                           uint4* __restrict__ meanb) {
    int w = __builtin_amdgcn_readfirstlane((int)(threadIdx.x >> 6));
    int node = blockIdx.x * 4 + w;
    int lane = threadIdx.x & 63;
    int q = lane >> 3, sl = lane & 7;
    int s0 = __builtin_amdgcn_readfirstlane(rowStart[node]);
    int cnt = __builtin_amdgcn_readfirstlane(hist[node]);
    float a[16];
#pragma unroll
    for (int e = 0; e < 16; e++) a[e] = 0.f;
    int i = 0;
    for (; i + 16 <= cnt; i += 16) {
        int sA = sortedSrc[s0 + i + q];
        int sB = sortedSrc[s0 + i + 8 + q];
        uint4 vA = xf8[(size_t)sA * 8 + sl];
        uint4 vB = xf8[(size_t)sB * 8 + sl];
        ACC4(vA)
        ACC4(vB)
    }
    for (; i + 8 <= cnt; i += 8) {
        int s = sortedSrc[s0 + i + q];
        uint4 v = xf8[(size_t)s * 8 + sl];
        ACC4(v)
    }
    if (q < cnt - i) {
        int s = sortedSrc[s0 + i + q];
        uint4 v = xf8[(size_t)s * 8 + sl];
        ACC4(v)
    }
#pragma unroll
    for (int e = 0; e < 16; e++) {
        a[e] += __shfl_xor(a[e], 8, 64);
        a[e] += __shfl_xor(a[e], 16, 64);
        a[e] += __shfl_xor(a[e], 32, 64);
    }
    if (q == 0) {
        float dinv = 1.0f / fmaxf((float)cnt, 1.0f);
        uint4 o1, o2;
        o1.x = (unsigned)f2bf(a[0] * dinv)  | ((unsigned)f2bf(a[1] * dinv) << 16);
        o1.y = (unsigned)f2bf(a[2] * dinv)  | ((unsigned)f2bf(a[3] * dinv) << 16);
        o1.z = (unsigned)f2bf(a[4] * dinv)  | ((unsigned)f2bf(a[5] * dinv) << 16);
        o1.w = (unsigned)f2bf(a[6] * dinv)  | ((unsigned)f2bf(a[7] * dinv) << 16);
        o2.x = (unsigned)f2bf(a[8] * dinv)  | ((unsigned)f2bf(a[9] * dinv) << 16);
        o2.y = (unsigned)f2bf(a[10] * dinv) | ((unsigned)f2bf(a[11] * dinv) << 16);
        o2.z = (unsigned)f2bf(a[12] * dinv) | ((unsigned)f2bf(a[13] * dinv) << 16);
        o2.w = (unsigned)f2bf(a[14] * dinv) | ((unsigned)f2bf(a[15] * dinv) << 16);
        meanb[(size_t)node * 16 + sl * 2] = o1;
        meanb[(size_t)node * 16 + sl * 2 + 1] = o2;
    }
}

// ---------------- layer-1 GEMM + norm + relu + layer-2 projection (2 MFMA passes) ----------------
__global__ __launch_bounds__(256) void gemm1g_kernel(
    const unsigned short* __restrict__ meanb, const unsigned short* __restrict__ xb,
    const short* __restrict__ bswz1, const float* __restrict__ bias1,
    const short* __restrict__ bswz2,
    unsigned short* __restrict__ g_l, unsigned short* __restrict__ g_r) {
    __shared__ unsigned short hT[4][16][140];
    int tid = threadIdx.x;
    int w = __builtin_amdgcn_readfirstlane(tid >> 6);
    int lane = tid & 63;
    int l15 = lane & 15, quad = lane >> 4;
    int n0 = blockIdx.x * 64;
    int nodeA = n0 + w * 16 + l15;
    if (nodeA >= N_NODES) nodeA = N_NODES - 1;

    float4v acc[8];
#pragma unroll
    for (int c = 0; c < 8; c++) acc[c] = (float4v){0.f, 0.f, 0.f, 0.f};
#pragma unroll
    for (int kt = 0; kt < 8; kt++) {
        const unsigned short* ab = (kt < 4) ? meanb : xb;
        short8 a = *(const short8*)(ab + (size_t)nodeA * 128 + (kt & 3) * 32 + quad * 8);
#pragma unroll
        for (int c = 0; c < 8; c++) {
            short8 b = *(const short8*)(bswz1 + (((kt * 8 + c) * 4 + quad) * 16 + l15) * 8);
            acc[c] = __builtin_amdgcn_mfma_f32_16x16x32_bf16(a, b, acc[c], 0, 0, 0);
        }
    }

    float v[8][4];
    float ss[4] = {0.f, 0.f, 0.f, 0.f};
#pragma unroll
    for (int c = 0; c < 8; c++) {
        float bi = bias1[c * 16 + l15];
#pragma unroll
        for (int r = 0; r < 4; r++) {
            float t = acc[c][r] + bi;
            v[c][r] = t;
            ss[r] += t * t;
        }
    }
#pragma unroll
    for (int r = 0; r < 4; r++)
        for (int off = 1; off < 16; off <<= 1) ss[r] += __shfl_xor(ss[r], off, 64);
#pragma unroll
    for (int r = 0; r < 4; r++) {
        float inv = 1.0f / fmaxf(sqrtf(ss[r]), EPSN);
#pragma unroll
        for (int c = 0; c < 8; c++) {
            hT[w][quad * 4 + r][c * 16 + l15] = f2bf(fmaxf(v[c][r] * inv, 0.0f));
        }
    }

    float4v acc2[8];
#pragma unroll
    for (int c = 0; c < 8; c++) acc2[c] = (float4v){0.f, 0.f, 0.f, 0.f};
#pragma unroll
    for (int kt = 0; kt < 4; kt++) {
        short8 a = *(const short8*)&hT[w][l15][kt * 32 + quad * 8];
#pragma unroll
        for (int c = 0; c < 8; c++) {
            short8 b = *(const short8*)(bswz2 + (((kt * 8 + c) * 4 + quad) * 16 + l15) * 8);
            acc2[c] = __builtin_amdgcn_mfma_f32_16x16x32_bf16(a, b, acc2[c], 0, 0, 0);
        }
    }
#pragma unroll
    for (int r = 0; r < 4; r++) {
        int node = n0 + w * 16 + quad * 4 + r;
        if (node < N_NODES) {
#pragma unroll
            for (int c = 0; c < 4; c++)
                g_l[(size_t)node * 64 + c * 16 + l15] = f2bf(acc2[c][r]);
#pragma unroll
            for (int c = 4; c < 8; c++)
                g_r[(size_t)node * 64 + (c - 4) * 16 + l15] = f2bf(acc2[c][r]);
        }
    }
}

// ---------------- layer 2 final: 4 nodes per wave ----------------
__global__ void fused2h_kernel(const uint4* __restrict__ g_l4, const uint4* __restrict__ g_r4,
                               const int* __restrict__ sortedSrc,
                               const int* __restrict__ rowStart, const int* __restrict__ hist,
                               const float* __restrict__ bias, float* __restrict__ out) {
    int tid = threadIdx.x;
    int w = __builtin_amdgcn_readfirstlane(tid >> 6);
    int lane = tid & 63;
    int g = lane >> 4, q1 = (lane >> 3) & 1, sl = lane & 7;
    int node = blockIdx.x * 16 + w * 4 + g;   // N_NODES % 16 == 0
    int s0 = rowStart[node];
    int cnt = hist[node];
    float a0 = 0.f, a1 = 0.f, a2 = 0.f, a3 = 0.f, a4 = 0.f, a5 = 0.f, a6 = 0.f, a7 = 0.f;
    int i = 0;
    for (; i + 4 <= cnt; i += 4) {
        int sA = sortedSrc[s0 + i + q1];
        int sB = sortedSrc[s0 + i + 2 + q1];
        uint4 vA = g_l4[(size_t)sA * 8 + sl];
        uint4 vB = g_l4[(size_t)sB * 8 + sl];
        a0 += bflo(vA.x) + bflo(vB.x); a1 += bfhi(vA.x) + bfhi(vB.x);
        a2 += bflo(vA.y) + bflo(vB.y); a3 += bfhi(vA.y) + bfhi(vB.y);
        a4 += bflo(vA.z) + bflo(vB.z); a5 += bfhi(vA.z) + bfhi(vB.z);
        a6 += bflo(vA.w) + bflo(vB.w); a7 += bfhi(vA.w) + bfhi(vB.w);
    }
    if (i + q1 < cnt) {
        int s = sortedSrc[s0 + i + q1];
        uint4 v = g_l4[(size_t)s * 8 + sl];
        a0 += bflo(v.x); a1 += bfhi(v.x); a2 += bflo(v.y); a3 += bfhi(v.y);
        a4 += bflo(v.z); a5 += bfhi(v.z); a6 += bflo(v.w); a7 += bfhi(v.w);
    }
    i += 2;
    if (i + q1 < cnt) {
        int s = sortedSrc[s0 + i + q1];
        uint4 v = g_l4[(size_t)s * 8 + sl];
        a0 += bflo(v.x); a1 += bfhi(v.x); a2 += bflo(v.y); a3 += bfhi(v.y);
        a4 += bflo(v.z); a5 += bfhi(v.z); a6 += bflo(v.w); a7 += bfhi(v.w);
    }
    a0 += __shfl_xor(a0, 8, 64);
    a1 += __shfl_xor(a1, 8, 64);
    a2 += __shfl_xor(a2, 8, 64);
    a3 += __shfl_xor(a3, 8, 64);
    a4 += __shfl_xor(a4, 8, 64);
    a5 += __shfl_xor(a5, 8, 64);
    a6 += __shfl_xor(a6, 8, 64);
    a7 += __shfl_xor(a7, 8, 64);
    float dinv = 1.0f / fmaxf((float)cnt, 1.0f);
    uint4 gr = g_r4[(size_t)node * 8 + sl];
    bool valid = (sl < 5);
    float b0 = 0, b1 = 0, b2 = 0, b3 = 0, b4 = 0, b5 = 0, b6 = 0, b7 = 0;
    if (valid) {
        b0 = bias[sl * 8 + 0]; b1 = bias[sl * 8 + 1]; b2 = bias[sl * 8 + 2]; b3 = bias[sl * 8 + 3];
        b4 = bias[sl * 8 + 4]; b5 = bias[sl * 8 + 5]; b6 = bias[sl * 8 + 6]; b7 = bias[sl * 8 + 7];
    }
    float t0 = a0 * dinv + bflo(gr.x) + b0;
    float t1 = a1 * dinv + bfhi(gr.x) + b1;
    float t2 = a2 * dinv + bflo(gr.y) + b2;
    float t3 = a3 * dinv + bfhi(gr.y) + b3;
    float t4 = a4 * dinv + bflo(gr.z) + b4;
    float t5 = a5 * dinv + bfhi(gr.z) + b5;
    float t6 = a6 * dinv + bflo(gr.w) + b6;
    float t7 = a7 * dinv + bfhi(gr.w) + b7;
    float ssq = t0 * t0 + t1 * t1 + t2 * t2 + t3 * t3 + t4 * t4 + t5 * t5 + t6 * t6 + t7 * t7;
    ssq += __shfl_xor(ssq, 1, 64); ssq += __shfl_xor(ssq, 2, 64); ssq += __shfl_xor(ssq, 4, 64);
    float inv = 1.0f / fmaxf(sqrtf(ssq), EPSN);
    float v0 = t0 * inv, v1 = t1 * inv, v2 = t2 * inv, v3 = t3 * inv;
    float v4 = t4 * inv, v5 = t5 * inv, v6 = t6 * inv, v7 = t7 * inv;
    float m = valid ? fmaxf(fmaxf(fmaxf(v0, v1), fmaxf(v2, v3)),
                            fmaxf(fmaxf(v4, v5), fmaxf(v6, v7))) : -INFINITY;
    m = fmaxf(m, __shfl_xor(m, 1, 64));
    m = fmaxf(m, __shfl_xor(m, 2, 64));
    m = fmaxf(m, __shfl_xor(m, 4, 64));
    float se = 0.0f;
    if (valid) {
        se = expf(v0 - m) + expf(v1 - m) + expf(v2 - m) + expf(v3 - m) +
             expf(v4 - m) + expf(v5 - m) + expf(v6 - m) + expf(v7 - m);
    }
    se += __shfl_xor(se, 1, 64); se += __shfl_xor(se, 2, 64); se += __shfl_xor(se, 4, 64);
    float ls = logf(se) + m;
    if (q1 == 0 && valid) {
        float* o = out + (size_t)node * D_OUT + sl * 8;
        ((float4*)o)[0] = (float4){v0 - ls, v1 - ls, v2 - ls, v3 - ls};
        ((float4*)o)[1] = (float4){v4 - ls, v5 - ls, v6 - ls, v7 - ls};
    }
}

static inline size_t align256(size_t x) { return (x + 255) & ~(size_t)255; }

extern "C" void kernel_launch(void* const* d_in, const int* in_sizes, int n_in,
                              void* d_out, int out_size, void* d_ws, size_t ws_size,
                              hipStream_t stream) {
    const float* x   = (const float*)d_in[0];
    const int*   ei  = (const int*)d_in[1];
    const float* Wl1 = (const float*)d_in[2];
    const float* bl1 = (const float*)d_in[3];
    const float* Wr1 = (const float*)d_in[4];
    const float* Wl2 = (const float*)d_in[5];
    const float* bl2 = (const float*)d_in[6];
    const float* Wr2 = (const float*)d_in[7];
    float* out = (float*)d_out;

    const int* src = ei;
    const int* dst = ei + N_EDGES;

    char* ws = (char*)d_ws;
    size_t off = 0;
    int* bucketCount = (int*)(ws + off); off += align256((size_t)NBUCK * 4);
    int* bucketStart = (int*)(ws + off); off += align256((size_t)(NBUCK + 1) * 4);
    int* cursor      = (int*)(ws + off); off += align256((size_t)NBUCK * 4);
    int* hist        = (int*)(ws + off); off += align256((size_t)N_NODES * 4);
    int* rowStart    = (int*)(ws + off); off += align256((size_t)N_NODES * 4);
    unsigned* pairs  = (unsigned*)(ws + off); off += align256((size_t)N_EDGES * 4);
    int* sortedSrc   = (int*)(ws + off); off += align256((size_t)N_EDGES * 4);
    unsigned* xb     = (unsigned*)(ws + off); off += align256((size_t)N_NODES * 128 * 2);
    unsigned* xf8    = (unsigned*)(ws + off); off += align256((size_t)N_NODES * 128);
    unsigned* meanb  = (unsigned*)(ws + off); off += align256((size_t)N_NODES * 128 * 2);
    unsigned short* g_l = (unsigned short*)(ws + off); off += align256((size_t)N_NODES * 64 * 2);
    unsigned short* g_r = (unsigned short*)(ws + off); off += align256((size_t)N_NODES * 64 * 2);
    unsigned short* bswz1 = (unsigned short*)(ws + off); off += align256((size_t)SWZ1_TOTAL * 2);
    unsigned short* bswz2 = (unsigned short*)(ws + off); off += align256((size_t)SWZ2_TOTAL * 2);

    hipMemsetAsync(bucketCount, 0, (size_t)NBUCK * 4, stream);

    prep_kernel<<<NPART + CASTB + F8B + SWZB, 256, 0, stream>>>(
        dst, bucketCount, x, xb, xf8, Wl1, Wr1, Wl2, Wr2, bswz1, bswz2);
    bscan_kernel<<<1, 256, 0, stream>>>(bucketCount, bucketStart, cursor);
    bpart_kernel<<<PNPART, 512, 0, stream>>>(src, dst, cursor, pairs);
    csr_kernel<<<NBUCK, 256, 0, stream>>>(pairs, bucketStart, hist, rowStart, sortedSrc);

    agg_kernel<<<N_NODES / 4, 256, 0, stream>>>((const uint4*)xf8, sortedSrc, rowStart, hist,
                                                (uint4*)meanb);
    gemm1g_kernel<<<(N_NODES + 63) / 64, 256, 0, stream>>>(
        (const unsigned short*)meanb, (const unsigned short*)xb,
        (const short*)bswz1, bl1, (const short*)bswz2, g_l, g_r);
    fused2h_kernel<<<N_NODES / 16, 256, 0, stream>>>(
        (const uint4*)g_l, (const uint4*)g_r, sortedSrc, rowStart, hist, bl2, out);
}